// Round 5
// baseline (348.949 us; speedup 1.0000x reference)
//
#include <hip/hip_runtime.h>

typedef unsigned short u16;
typedef unsigned int u32;
typedef __attribute__((ext_vector_type(8))) short short8;
typedef __attribute__((ext_vector_type(4))) float f32x4;

#define NN 20000
#define EE 640000

__device__ inline u16 f2bf(float f) {
    u32 x = __float_as_uint(f);
    return (u16)((x + 0x7FFFu + ((x >> 16) & 1u)) >> 16);
}
__device__ inline float lo16(u32 w) { return __uint_as_float(w << 16); }
__device__ inline float hi16(u32 w) { return __uint_as_float(w & 0xFFFF0000u); }
__device__ inline u32 packbf(float a, float b) { return ((u32)f2bf(b) << 16) | (u32)f2bf(a); }

// ---------------- zero ints ----------------
__global__ void zero_ints(int* p, int n) {
    int i = blockIdx.x * 256 + threadIdx.x;
    if (i < n) p[i] = 0;
}

// ---------------- cast x -> bf16 rows ----------------
__global__ void cast_x(const float* __restrict__ x, u16* __restrict__ xb) {
    int i = blockIdx.x * 256 + threadIdx.x;   // one float4 per thread
    if (i >= NN * 32) return;
    float4 v = *(const float4*)(x + (size_t)i * 4);
    uint2 o;
    o.x = packbf(v.x, v.y);
    o.y = packbf(v.z, v.w);
    *(uint2*)(xb + (size_t)i * 4) = o;
}

// ---------------- weight prep: cast f32->bf16, transpose to [out][k] ----------------
__global__ void prep_weights(const float* rw, const float* root,
                             const float* Wq, const float* Wk, const float* Wv, const float* Ws,
                             const float* bq, const float* bk, const float* bv, const float* bs,
                             u16* wt1, u16* wt2, float* bcat) {
    int idx = blockIdx.x * 256 + threadIdx.x;
    const int S1 = 128 * 1152, S2 = 4 * 128 * 128;
    if (idx < S1) {
        int o = idx / 1152, k = idx - o * 1152;
        float v = (k < 1024) ? rw[k * 128 + o] : root[(k - 1024) * 128 + o];
        wt1[idx] = f2bf(v);
    } else if (idx < S1 + S2) {
        int j = idx - S1;
        int y = j >> 14, rem = j & 16383, o = rem >> 7, i = rem & 127;
        const float* W = (y == 0) ? Wq : (y == 1) ? Wk : (y == 2) ? Wv : Ws;
        wt2[j] = f2bf(W[i * 128 + o]);
    } else if (idx < S1 + S2 + 512) {
        int j = idx - (S1 + S2);
        int y = j >> 7, c = j & 127;
        const float* b = (y == 0) ? bq : (y == 1) ? bk : (y == 2) ? bv : bs;
        bcat[j] = b[c];
    }
}

// ---------------- CSR build: one atomic per edge; returned old value = rank ----------------
__global__ void count_rank(const int* __restrict__ ei, const int* __restrict__ et,
                           int* __restrict__ cnt, int* __restrict__ rank) {
    int e = blockIdx.x * 256 + threadIdx.x;
    if (e >= EE) return;
    int dst = ei[EE + e];
    int r = et[e];
    rank[e] = atomicAdd(&cnt[dst * 8 + r], 1);
}

// scan over nodes: deg[n] = sum_r cnt[n][r]; writes row_off AND per-(node,rel) starts srt
__global__ void scan_kernel(const int* __restrict__ cnt, int* __restrict__ row_off,
                            int* __restrict__ srt) {
    __shared__ int sums[1024];
    int t = threadIdx.x;
    const int CH = 20;
    int base = t * CH;
    int degl[CH];
    int s = 0;
    for (int i = 0; i < CH; i++) {
        int id = base + i;
        int d = 0;
        if (id < NN) {
            int4 c0 = *(const int4*)(cnt + id * 8);
            int4 c1 = *(const int4*)(cnt + id * 8 + 4);
            d = c0.x + c0.y + c0.z + c0.w + c1.x + c1.y + c1.z + c1.w;
        }
        degl[i] = d;
        s += d;
    }
    sums[t] = s;
    __syncthreads();
    for (int o = 1; o < 1024; o <<= 1) {
        int vadd = 0;
        if (t >= o) vadd = sums[t - o];
        __syncthreads();
        sums[t] += vadd;
        __syncthreads();
    }
    int run = (t > 0) ? sums[t - 1] : 0;
    for (int i = 0; i < CH; i++) {
        int id = base + i;
        if (id < NN) {
            row_off[id] = run;
            int sub = run;
#pragma unroll
            for (int r = 0; r < 8; r++) {
                srt[id * 8 + r] = sub;
                sub += cnt[id * 8 + r];
            }
            run += degl[i];
            if (id == NN - 1) row_off[NN] = run;
        }
    }
}

// atomic-free scatter using precomputed ranks
__global__ void scatter_kernel(const int* __restrict__ ei, const int* __restrict__ et,
                               const int* __restrict__ srt, const int* __restrict__ rank,
                               int* __restrict__ es) {
    int e = blockIdx.x * 256 + threadIdx.x;
    if (e >= EE) return;
    int dst = ei[EE + e];
    int src = ei[e];
    int r = et[e];
    int pos = srt[dst * 8 + r] + rank[e];
    es[pos] = src;
}

// ---------------- RGCN pre-aggregation: half-wave per node, 4x edge ILP, bf16 gathers ----------------
__global__ __launch_bounds__(256) void rgcn_agg(const u16* __restrict__ xb,
                                                const int* __restrict__ srt,
                                                const int* __restrict__ cnt,
                                                const int* __restrict__ es,
                                                u16* __restrict__ pre) {
    int node = blockIdx.x * 8 + (threadIdx.x >> 5);
    int lane = threadIdx.x & 31;     // 4 dims/lane
    if (node >= NN) return;
    // copy x row into tail (fuses root projection into the big GEMM)
    uint2 xv = *(const uint2*)(xb + (long)node * 128 + lane * 4);
    *(uint2*)(pre + (long)node * 1152 + 1024 + lane * 4) = xv;
#pragma unroll 1
    for (int r = 0; r < 8; r++) {
        int c = cnt[node * 8 + r];
        int p0 = srt[node * 8 + r];
        float inv = 1.0f / (float)(c > 1 ? c : 1);
        float4 a = {0.f, 0.f, 0.f, 0.f};
        int i = 0;
        for (; i + 4 <= c; i += 4) {
            int s0 = es[p0 + i], s1 = es[p0 + i + 1], s2 = es[p0 + i + 2], s3 = es[p0 + i + 3];
            uint2 w0 = *(const uint2*)(xb + (long)s0 * 128 + lane * 4);
            uint2 w1 = *(const uint2*)(xb + (long)s1 * 128 + lane * 4);
            uint2 w2 = *(const uint2*)(xb + (long)s2 * 128 + lane * 4);
            uint2 w3 = *(const uint2*)(xb + (long)s3 * 128 + lane * 4);
            a.x += (lo16(w0.x) + lo16(w1.x)) + (lo16(w2.x) + lo16(w3.x));
            a.y += (hi16(w0.x) + hi16(w1.x)) + (hi16(w2.x) + hi16(w3.x));
            a.z += (lo16(w0.y) + lo16(w1.y)) + (lo16(w2.y) + lo16(w3.y));
            a.w += (hi16(w0.y) + hi16(w1.y)) + (hi16(w2.y) + hi16(w3.y));
        }
        for (; i < c; i++) {
            int s = es[p0 + i];
            uint2 w = *(const uint2*)(xb + (long)s * 128 + lane * 4);
            a.x += lo16(w.x); a.y += hi16(w.x); a.z += lo16(w.y); a.w += hi16(w.y);
        }
        uint2 ow;
        ow.x = packbf(a.x * inv, a.y * inv);
        ow.y = packbf(a.z * inv, a.w * inv);
        *(uint2*)(pre + (long)node * 1152 + r * 128 + lane * 4) = ow;
    }
}

// ---------------- MFMA GEMM: C[rows x 128] = A[rows x K] * Bt^T + bias (opt relu) ----------------
__global__ __launch_bounds__(256) void gemm_kernel(const u16* __restrict__ A, int lda,
                                                   const u16* __restrict__ Bt, int ldbt,
                                                   const float* __restrict__ bias,
                                                   u16* __restrict__ C, int ldc,
                                                   int rows, int K, int relu,
                                                   long long yBt, long long yC, long long yBias) {
    Bt += blockIdx.y * yBt;
    C += blockIdx.y * yC;
    bias += blockIdx.y * yBias;
    __shared__ u16 As[64 * 136];
    __shared__ u16 Bs[128 * 136];
    int tid = threadIdx.x;
    int w = tid >> 6;
    int lane = tid & 63;
    int quad = lane >> 4;
    int ml = lane & 15;
    int block_m = blockIdx.x * 64;

    f32x4 acc[8];
#pragma unroll
    for (int i = 0; i < 8; i++) acc[i] = (f32x4){0.f, 0.f, 0.f, 0.f};

    int rbase = tid >> 4;
    int cb = (tid & 15) * 8;

    for (int kb = 0; kb < K; kb += 128) {
#pragma unroll
        for (int rep = 0; rep < 4; rep++) {
            int r = rbase + rep * 16;
            int gr = block_m + r;
            short8 val = {};
            if (gr < rows) val = *(const short8*)(A + (long)gr * lda + kb + cb);
            *(short8*)(As + r * 136 + cb) = val;
        }
#pragma unroll
        for (int rep = 0; rep < 8; rep++) {
            int r = rbase + rep * 16;
            short8 val = *(const short8*)(Bt + (long)r * ldbt + kb + cb);
            *(short8*)(Bs + r * 136 + cb) = val;
        }
        __syncthreads();
#pragma unroll
        for (int ks = 0; ks < 4; ks++) {
            short8 af = *(const short8*)(As + (w * 16 + ml) * 136 + ks * 32 + quad * 8);
#pragma unroll
            for (int nt = 0; nt < 8; nt++) {
                short8 bfr = *(const short8*)(Bs + (nt * 16 + ml) * 136 + ks * 32 + quad * 8);
                acc[nt] = __builtin_amdgcn_mfma_f32_16x16x32_bf16(af, bfr, acc[nt], 0, 0, 0);
            }
        }
        __syncthreads();
    }
#pragma unroll
    for (int nt = 0; nt < 8; nt++) {
        int col = nt * 16 + ml;
        float bv = bias[col];
#pragma unroll
        for (int i = 0; i < 4; i++) {
            int gr = block_m + w * 16 + quad * 4 + i;
            if (gr < rows) {
                float vv = acc[nt][i] + bv;
                if (relu) vv = fmaxf(vv, 0.f);
                C[(long)gr * ldc + col] = f2bf(vv);
            }
        }
    }
}

// ---------------- attention: half-wave per node, 4x edge ILP, online softmax ----------------
__global__ __launch_bounds__(256) void attn_kernel(const u16* __restrict__ q, const u16* __restrict__ k,
                                                   const u16* __restrict__ v, const u16* __restrict__ skip,
                                                   const int* __restrict__ row_off, const int* __restrict__ es,
                                                   float* __restrict__ out) {
    int node = blockIdx.x * 8 + (threadIdx.x >> 5);
    int lane = threadIdx.x & 31;     // 4 dims/lane
    if (node >= NN) return;
    int p0 = row_off[node], p1 = row_off[node + 1];
    uint2 qw = *(const uint2*)(q + (long)node * 128 + lane * 4);
    float q0 = lo16(qw.x), q1 = hi16(qw.x), q2 = lo16(qw.y), q3 = hi16(qw.y);
    const float SC = 0.08838834764831845f;  // 1/sqrt(128)
    float m = -INFINITY, l = 0.f;
    float4 a = {0.f, 0.f, 0.f, 0.f};
    int p = p0;
    for (; p + 4 <= p1; p += 4) {
        int s0 = es[p], s1 = es[p + 1], s2 = es[p + 2], s3 = es[p + 3];
        uint2 k0 = *(const uint2*)(k + (long)s0 * 128 + lane * 4);
        uint2 k1 = *(const uint2*)(k + (long)s1 * 128 + lane * 4);
        uint2 k2 = *(const uint2*)(k + (long)s2 * 128 + lane * 4);
        uint2 k3 = *(const uint2*)(k + (long)s3 * 128 + lane * 4);
        uint2 v0 = *(const uint2*)(v + (long)s0 * 128 + lane * 4);
        uint2 v1 = *(const uint2*)(v + (long)s1 * 128 + lane * 4);
        uint2 v2 = *(const uint2*)(v + (long)s2 * 128 + lane * 4);
        uint2 v3 = *(const uint2*)(v + (long)s3 * 128 + lane * 4);
        float t0 = q0 * lo16(k0.x) + q1 * hi16(k0.x) + q2 * lo16(k0.y) + q3 * hi16(k0.y);
        float t1 = q0 * lo16(k1.x) + q1 * hi16(k1.x) + q2 * lo16(k1.y) + q3 * hi16(k1.y);
        float t2 = q0 * lo16(k2.x) + q1 * hi16(k2.x) + q2 * lo16(k2.y) + q3 * hi16(k2.y);
        float t3 = q0 * lo16(k3.x) + q1 * hi16(k3.x) + q2 * lo16(k3.y) + q3 * hi16(k3.y);
#pragma unroll
        for (int off = 16; off >= 1; off >>= 1) {
            t0 += __shfl_xor(t0, off, 32);
            t1 += __shfl_xor(t1, off, 32);
            t2 += __shfl_xor(t2, off, 32);
            t3 += __shfl_xor(t3, off, 32);
        }
        t0 *= SC; t1 *= SC; t2 *= SC; t3 *= SC;
        float mx = fmaxf(fmaxf(t0, t1), fmaxf(t2, t3));
        float mn = fmaxf(m, mx);
        float scale = __expf(m - mn);
        float w0 = __expf(t0 - mn), w1 = __expf(t1 - mn), w2 = __expf(t2 - mn), w3 = __expf(t3 - mn);
        l = l * scale + ((w0 + w1) + (w2 + w3));
        a.x = a.x * scale + w0 * lo16(v0.x) + w1 * lo16(v1.x) + w2 * lo16(v2.x) + w3 * lo16(v3.x);
        a.y = a.y * scale + w0 * hi16(v0.x) + w1 * hi16(v1.x) + w2 * hi16(v2.x) + w3 * hi16(v3.x);
        a.z = a.z * scale + w0 * lo16(v0.y) + w1 * lo16(v1.y) + w2 * lo16(v2.y) + w3 * lo16(v3.y);
        a.w = a.w * scale + w0 * hi16(v0.y) + w1 * hi16(v1.y) + w2 * hi16(v2.y) + w3 * hi16(v3.y);
        m = mn;
    }
    for (; p < p1; p++) {
        int s = es[p];
        uint2 kw = *(const uint2*)(k + (long)s * 128 + lane * 4);
        uint2 vw = *(const uint2*)(v + (long)s * 128 + lane * 4);
        float t = q0 * lo16(kw.x) + q1 * hi16(kw.x) + q2 * lo16(kw.y) + q3 * hi16(kw.y);
#pragma unroll
        for (int off = 16; off >= 1; off >>= 1) t += __shfl_xor(t, off, 32);
        t *= SC;
        float mn = fmaxf(m, t);
        float scale = __expf(m - mn);
        float wgt = __expf(t - mn);
        l = l * scale + wgt;
        a.x = a.x * scale + wgt * lo16(vw.x);
        a.y = a.y * scale + wgt * hi16(vw.x);
        a.z = a.z * scale + wgt * lo16(vw.y);
        a.w = a.w * scale + wgt * hi16(vw.y);
        m = mn;
    }
    float invl = (l > 0.f) ? 1.0f / l : 0.f;
    uint2 sw = *(const uint2*)(skip + (long)node * 128 + lane * 4);
    float4 o4;
    o4.x = fmaxf(a.x * invl + lo16(sw.x), 0.f);
    o4.y = fmaxf(a.y * invl + hi16(sw.x), 0.f);
    o4.z = fmaxf(a.z * invl + lo16(sw.y), 0.f);
    o4.w = fmaxf(a.w * invl + hi16(sw.y), 0.f);
    *(float4*)(out + (long)node * 128 + lane * 4) = o4;
}

extern "C" void kernel_launch(void* const* d_in, const int* in_sizes, int n_in,
                              void* d_out, int out_size, void* d_ws, size_t ws_size,
                              hipStream_t stream) {
    const float* x = (const float*)d_in[0];
    const int* ei = (const int*)d_in[1];
    const int* et = (const int*)d_in[2];
    const float* rw = (const float*)d_in[3];
    const float* root = (const float*)d_in[4];
    const float* rbias = (const float*)d_in[5];
    const float* Wq = (const float*)d_in[6];
    const float* bq = (const float*)d_in[7];
    const float* Wk = (const float*)d_in[8];
    const float* bk = (const float*)d_in[9];
    const float* Wv = (const float*)d_in[10];
    const float* bv = (const float*)d_in[11];
    const float* Ws = (const float*)d_in[12];
    const float* bs = (const float*)d_in[13];

    char* ws = (char*)d_ws;
    size_t off = 0;
    auto alloc = [&](size_t b) {
        size_t o = off;
        off = (off + b + 255) & ~(size_t)255;
        return o;
    };
    u16* pre = (u16*)(ws + alloc((size_t)NN * 1152 * 2));
    u16* h = (u16*)(ws + alloc((size_t)NN * 128 * 2));
    u16* qkvs = (u16*)(ws + alloc((size_t)4 * NN * 128 * 2));
    u16* xb = (u16*)(ws + alloc((size_t)NN * 128 * 2));
    u16* wt1 = (u16*)(ws + alloc((size_t)128 * 1152 * 2));
    u16* wt2 = (u16*)(ws + alloc((size_t)4 * 128 * 128 * 2));
    float* bcat = (float*)(ws + alloc((size_t)512 * 4));
    int* cnt = (int*)(ws + alloc((size_t)NN * 8 * 4));
    int* row_off = (int*)(ws + alloc((size_t)(NN + 1) * 4));
    int* srt = (int*)(ws + alloc((size_t)NN * 8 * 4));
    int* rank = (int*)(ws + alloc((size_t)EE * 4));
    int* es = (int*)(ws + alloc((size_t)EE * 4));
    (void)ws_size;
    (void)in_sizes;
    (void)n_in;
    (void)out_size;

    zero_ints<<<(NN * 8 + 255) / 256, 256, 0, stream>>>(cnt, NN * 8);

    cast_x<<<(NN * 32 + 255) / 256, 256, 0, stream>>>(x, xb);

    prep_weights<<<(128 * 1152 + 4 * 128 * 128 + 512 + 255) / 256, 256, 0, stream>>>(
        rw, root, Wq, Wk, Wv, Ws, bq, bk, bv, bs, wt1, wt2, bcat);

    count_rank<<<EE / 256, 256, 0, stream>>>(ei, et, cnt, rank);
    scan_kernel<<<1, 1024, 0, stream>>>(cnt, row_off, srt);
    scatter_kernel<<<EE / 256, 256, 0, stream>>>(ei, et, srt, rank, es);

    rgcn_agg<<<(NN + 7) / 8, 256, 0, stream>>>(xb, srt, cnt, es, pre);

    gemm_kernel<<<dim3((NN + 63) / 64, 1), 256, 0, stream>>>(pre, 1152, wt1, 1152, rbias, h, 128,
                                                             NN, 1152, 1, 0, 0, 0);
    gemm_kernel<<<dim3((NN + 63) / 64, 4), 256, 0, stream>>>(h, 128, wt2, 128, bcat, qkvs, 128,
                                                             NN, 128, 0, (long long)128 * 128,
                                                             (long long)NN * 128, 128);

    attn_kernel<<<(NN + 7) / 8, 256, 0, stream>>>(qkvs, qkvs + (size_t)NN * 128, qkvs + (size_t)2 * NN * 128,
                                                  qkvs + (size_t)3 * NN * 128, row_off, es, (float*)d_out);
}

// Round 6
// 279.135 us; speedup vs baseline: 1.2501x; 1.2501x over previous
//
#include <hip/hip_runtime.h>

typedef unsigned short u16;
typedef unsigned int u32;
typedef __attribute__((ext_vector_type(8))) short short8;
typedef __attribute__((ext_vector_type(4))) float f32x4;

#define NN 20000
#define EE 640000
#define SCAN_BLOCKS 80   // 80*256 = 20480 >= NN

__device__ inline u16 f2bf(float f) {
    u32 x = __float_as_uint(f);
    return (u16)((x + 0x7FFFu + ((x >> 16) & 1u)) >> 16);
}
__device__ inline float lo16(u32 w) { return __uint_as_float(w << 16); }
__device__ inline float hi16(u32 w) { return __uint_as_float(w & 0xFFFF0000u); }
__device__ inline u32 packbf(float a, float b) { return ((u32)f2bf(b) << 16) | (u32)f2bf(a); }

// ---------------- zero ints ----------------
__global__ void zero_ints(int* p, int n) {
    int i = blockIdx.x * 256 + threadIdx.x;
    if (i < n) p[i] = 0;
}

// ---------------- cast x -> bf16 rows ----------------
__global__ void cast_x(const float* __restrict__ x, u16* __restrict__ xb) {
    int i = blockIdx.x * 256 + threadIdx.x;   // one float4 per thread
    if (i >= NN * 32) return;
    float4 v = *(const float4*)(x + (size_t)i * 4);
    uint2 o;
    o.x = packbf(v.x, v.y);
    o.y = packbf(v.z, v.w);
    *(uint2*)(xb + (size_t)i * 4) = o;
}

// ---------------- weight prep: cast f32->bf16, transpose to [out][k] ----------------
__global__ void prep_weights(const float* rw, const float* root,
                             const float* Wq, const float* Wk, const float* Wv, const float* Ws,
                             const float* bq, const float* bk, const float* bv, const float* bs,
                             u16* wt1, u16* wt2, float* bcat) {
    int idx = blockIdx.x * 256 + threadIdx.x;
    const int S1 = 128 * 1152, S2 = 4 * 128 * 128;
    if (idx < S1) {
        int o = idx / 1152, k = idx - o * 1152;
        float v = (k < 1024) ? rw[k * 128 + o] : root[(k - 1024) * 128 + o];
        wt1[idx] = f2bf(v);
    } else if (idx < S1 + S2) {
        int j = idx - S1;
        int y = j >> 14, rem = j & 16383, o = rem >> 7, i = rem & 127;
        const float* W = (y == 0) ? Wq : (y == 1) ? Wk : (y == 2) ? Wv : Ws;
        wt2[j] = f2bf(W[i * 128 + o]);
    } else if (idx < S1 + S2 + 512) {
        int j = idx - (S1 + S2);
        int y = j >> 7, c = j & 127;
        const float* b = (y == 0) ? bq : (y == 1) ? bk : (y == 2) ? bv : bs;
        bcat[j] = b[c];
    }
}

// ---------------- CSR build: one atomic per edge; returned old value = rank ----------------
__global__ void count_rank(const int* __restrict__ ei, const int* __restrict__ et,
                           int* __restrict__ cnt, int* __restrict__ rank) {
    int e = blockIdx.x * 256 + threadIdx.x;
    if (e >= EE) return;
    int dst = ei[EE + e];
    int r = et[e];
    rank[e] = atomicAdd(&cnt[dst * 8 + r], 1);
}

// ---------------- parallel 3-phase scan ----------------
// phase1: per-node degree, intra-block inclusive scan, block totals
__global__ __launch_bounds__(256) void scan_phase1(const int* __restrict__ cnt,
                                                   int* __restrict__ deg_pref,
                                                   int* __restrict__ blk_sums) {
    __shared__ int lds[256];
    int t = threadIdx.x;
    int n = blockIdx.x * 256 + t;
    int d = 0;
    if (n < NN) {
        int4 c0 = *(const int4*)(cnt + n * 8);
        int4 c1 = *(const int4*)(cnt + n * 8 + 4);
        d = c0.x + c0.y + c0.z + c0.w + c1.x + c1.y + c1.z + c1.w;
    }
    lds[t] = d;
    __syncthreads();
    for (int o = 1; o < 256; o <<= 1) {
        int v = (t >= o) ? lds[t - o] : 0;
        __syncthreads();
        lds[t] += v;
        __syncthreads();
    }
    if (n < NN) deg_pref[n] = lds[t];            // inclusive prefix within block
    if (t == 255) blk_sums[blockIdx.x] = lds[255];
}

// phase2: scan the block sums (exclusive), single tiny block
__global__ void scan_phase2(int* __restrict__ blk_sums) {
    __shared__ int lds[128];
    int t = threadIdx.x;
    int v = (t < SCAN_BLOCKS) ? blk_sums[t] : 0;
    lds[t] = v;
    __syncthreads();
    for (int o = 1; o < 128; o <<= 1) {
        int a = (t >= o) ? lds[t - o] : 0;
        __syncthreads();
        lds[t] += a;
        __syncthreads();
    }
    if (t < SCAN_BLOCKS) blk_sums[t] = lds[t] - v;   // exclusive
}

// phase3: global offsets -> row_off + per-(node,rel) starts srt
__global__ __launch_bounds__(256) void scan_phase3(const int* __restrict__ cnt,
                                                   const int* __restrict__ deg_pref,
                                                   const int* __restrict__ blk_sums,
                                                   int* __restrict__ row_off,
                                                   int* __restrict__ srt) {
    int n = blockIdx.x * 256 + threadIdx.x;
    if (n >= NN) return;
    int4 c0 = *(const int4*)(cnt + n * 8);
    int4 c1 = *(const int4*)(cnt + n * 8 + 4);
    int deg = c0.x + c0.y + c0.z + c0.w + c1.x + c1.y + c1.z + c1.w;
    int start = blk_sums[blockIdx.x] + deg_pref[n] - deg;   // exclusive global prefix
    row_off[n] = start;
    int sub = start;
    int o[8];
    o[0] = sub; sub += c0.x;
    o[1] = sub; sub += c0.y;
    o[2] = sub; sub += c0.z;
    o[3] = sub; sub += c0.w;
    o[4] = sub; sub += c1.x;
    o[5] = sub; sub += c1.y;
    o[6] = sub; sub += c1.z;
    o[7] = sub; sub += c1.w;
    *(int4*)(srt + n * 8) = make_int4(o[0], o[1], o[2], o[3]);
    *(int4*)(srt + n * 8 + 4) = make_int4(o[4], o[5], o[6], o[7]);
    if (n == NN - 1) row_off[NN] = sub;
}

// atomic-free scatter using precomputed ranks
__global__ void scatter_kernel(const int* __restrict__ ei, const int* __restrict__ et,
                               const int* __restrict__ srt, const int* __restrict__ rank,
                               int* __restrict__ es) {
    int e = blockIdx.x * 256 + threadIdx.x;
    if (e >= EE) return;
    int dst = ei[EE + e];
    int src = ei[e];
    int r = et[e];
    int pos = srt[dst * 8 + r] + rank[e];
    es[pos] = src;
}

// ---------------- RGCN pre-aggregation: half-wave per node, 4x edge ILP, bf16 gathers ----------------
__global__ __launch_bounds__(256) void rgcn_agg(const u16* __restrict__ xb,
                                                const int* __restrict__ srt,
                                                const int* __restrict__ cnt,
                                                const int* __restrict__ es,
                                                u16* __restrict__ pre) {
    int node = blockIdx.x * 8 + (threadIdx.x >> 5);
    int lane = threadIdx.x & 31;     // 4 dims/lane
    if (node >= NN) return;
    // copy x row into tail (fuses root projection into the big GEMM)
    uint2 xv = *(const uint2*)(xb + (long)node * 128 + lane * 4);
    *(uint2*)(pre + (long)node * 1152 + 1024 + lane * 4) = xv;
#pragma unroll 1
    for (int r = 0; r < 8; r++) {
        int c = cnt[node * 8 + r];
        int p0 = srt[node * 8 + r];
        float inv = 1.0f / (float)(c > 1 ? c : 1);
        float4 a = {0.f, 0.f, 0.f, 0.f};
        int i = 0;
        for (; i + 4 <= c; i += 4) {
            int s0 = es[p0 + i], s1 = es[p0 + i + 1], s2 = es[p0 + i + 2], s3 = es[p0 + i + 3];
            uint2 w0 = *(const uint2*)(xb + (long)s0 * 128 + lane * 4);
            uint2 w1 = *(const uint2*)(xb + (long)s1 * 128 + lane * 4);
            uint2 w2 = *(const uint2*)(xb + (long)s2 * 128 + lane * 4);
            uint2 w3 = *(const uint2*)(xb + (long)s3 * 128 + lane * 4);
            a.x += (lo16(w0.x) + lo16(w1.x)) + (lo16(w2.x) + lo16(w3.x));
            a.y += (hi16(w0.x) + hi16(w1.x)) + (hi16(w2.x) + hi16(w3.x));
            a.z += (lo16(w0.y) + lo16(w1.y)) + (lo16(w2.y) + lo16(w3.y));
            a.w += (hi16(w0.y) + hi16(w1.y)) + (hi16(w2.y) + hi16(w3.y));
        }
        for (; i < c; i++) {
            int s = es[p0 + i];
            uint2 w = *(const uint2*)(xb + (long)s * 128 + lane * 4);
            a.x += lo16(w.x); a.y += hi16(w.x); a.z += lo16(w.y); a.w += hi16(w.y);
        }
        uint2 ow;
        ow.x = packbf(a.x * inv, a.y * inv);
        ow.y = packbf(a.z * inv, a.w * inv);
        *(uint2*)(pre + (long)node * 1152 + r * 128 + lane * 4) = ow;
    }
}

// ---------------- MFMA GEMM: C[rows x 128] = A[rows x K] * Bt^T + bias (opt relu) ----------------
__global__ __launch_bounds__(256) void gemm_kernel(const u16* __restrict__ A, int lda,
                                                   const u16* __restrict__ Bt, int ldbt,
                                                   const float* __restrict__ bias,
                                                   u16* __restrict__ C, int ldc,
                                                   int rows, int K, int relu,
                                                   long long yBt, long long yC, long long yBias) {
    Bt += blockIdx.y * yBt;
    C += blockIdx.y * yC;
    bias += blockIdx.y * yBias;
    __shared__ u16 As[64 * 136];
    __shared__ u16 Bs[128 * 136];
    int tid = threadIdx.x;
    int w = tid >> 6;
    int lane = tid & 63;
    int quad = lane >> 4;
    int ml = lane & 15;
    int block_m = blockIdx.x * 64;

    f32x4 acc[8];
#pragma unroll
    for (int i = 0; i < 8; i++) acc[i] = (f32x4){0.f, 0.f, 0.f, 0.f};

    int rbase = tid >> 4;
    int cb = (tid & 15) * 8;

    for (int kb = 0; kb < K; kb += 128) {
#pragma unroll
        for (int rep = 0; rep < 4; rep++) {
            int r = rbase + rep * 16;
            int gr = block_m + r;
            short8 val = {};
            if (gr < rows) val = *(const short8*)(A + (long)gr * lda + kb + cb);
            *(short8*)(As + r * 136 + cb) = val;
        }
#pragma unroll
        for (int rep = 0; rep < 8; rep++) {
            int r = rbase + rep * 16;
            short8 val = *(const short8*)(Bt + (long)r * ldbt + kb + cb);
            *(short8*)(Bs + r * 136 + cb) = val;
        }
        __syncthreads();
#pragma unroll
        for (int ks = 0; ks < 4; ks++) {
            short8 af = *(const short8*)(As + (w * 16 + ml) * 136 + ks * 32 + quad * 8);
#pragma unroll
            for (int nt = 0; nt < 8; nt++) {
                short8 bfr = *(const short8*)(Bs + (nt * 16 + ml) * 136 + ks * 32 + quad * 8);
                acc[nt] = __builtin_amdgcn_mfma_f32_16x16x32_bf16(af, bfr, acc[nt], 0, 0, 0);
            }
        }
        __syncthreads();
    }
#pragma unroll
    for (int nt = 0; nt < 8; nt++) {
        int col = nt * 16 + ml;
        float bv = bias[col];
#pragma unroll
        for (int i = 0; i < 4; i++) {
            int gr = block_m + w * 16 + quad * 4 + i;
            if (gr < rows) {
                float vv = acc[nt][i] + bv;
                if (relu) vv = fmaxf(vv, 0.f);
                C[(long)gr * ldc + col] = f2bf(vv);
            }
        }
    }
}

// ---------------- attention: half-wave per node, 4x edge ILP, online softmax ----------------
__global__ __launch_bounds__(256) void attn_kernel(const u16* __restrict__ q, const u16* __restrict__ k,
                                                   const u16* __restrict__ v, const u16* __restrict__ skip,
                                                   const int* __restrict__ row_off, const int* __restrict__ es,
                                                   float* __restrict__ out) {
    int node = blockIdx.x * 8 + (threadIdx.x >> 5);
    int lane = threadIdx.x & 31;     // 4 dims/lane
    if (node >= NN) return;
    int p0 = row_off[node], p1 = row_off[node + 1];
    uint2 qw = *(const uint2*)(q + (long)node * 128 + lane * 4);
    float q0 = lo16(qw.x), q1 = hi16(qw.x), q2 = lo16(qw.y), q3 = hi16(qw.y);
    const float SC = 0.08838834764831845f;  // 1/sqrt(128)
    float m = -INFINITY, l = 0.f;
    float4 a = {0.f, 0.f, 0.f, 0.f};
    int p = p0;
    for (; p + 4 <= p1; p += 4) {
        int s0 = es[p], s1 = es[p + 1], s2 = es[p + 2], s3 = es[p + 3];
        uint2 k0 = *(const uint2*)(k + (long)s0 * 128 + lane * 4);
        uint2 k1 = *(const uint2*)(k + (long)s1 * 128 + lane * 4);
        uint2 k2 = *(const uint2*)(k + (long)s2 * 128 + lane * 4);
        uint2 k3 = *(const uint2*)(k + (long)s3 * 128 + lane * 4);
        uint2 v0 = *(const uint2*)(v + (long)s0 * 128 + lane * 4);
        uint2 v1 = *(const uint2*)(v + (long)s1 * 128 + lane * 4);
        uint2 v2 = *(const uint2*)(v + (long)s2 * 128 + lane * 4);
        uint2 v3 = *(const uint2*)(v + (long)s3 * 128 + lane * 4);
        float t0 = q0 * lo16(k0.x) + q1 * hi16(k0.x) + q2 * lo16(k0.y) + q3 * hi16(k0.y);
        float t1 = q0 * lo16(k1.x) + q1 * hi16(k1.x) + q2 * lo16(k1.y) + q3 * hi16(k1.y);
        float t2 = q0 * lo16(k2.x) + q1 * hi16(k2.x) + q2 * lo16(k2.y) + q3 * hi16(k2.y);
        float t3 = q0 * lo16(k3.x) + q1 * hi16(k3.x) + q2 * lo16(k3.y) + q3 * hi16(k3.y);
#pragma unroll
        for (int off = 16; off >= 1; off >>= 1) {
            t0 += __shfl_xor(t0, off, 32);
            t1 += __shfl_xor(t1, off, 32);
            t2 += __shfl_xor(t2, off, 32);
            t3 += __shfl_xor(t3, off, 32);
        }
        t0 *= SC; t1 *= SC; t2 *= SC; t3 *= SC;
        float mx = fmaxf(fmaxf(t0, t1), fmaxf(t2, t3));
        float mn = fmaxf(m, mx);
        float scale = __expf(m - mn);
        float w0 = __expf(t0 - mn), w1 = __expf(t1 - mn), w2 = __expf(t2 - mn), w3 = __expf(t3 - mn);
        l = l * scale + ((w0 + w1) + (w2 + w3));
        a.x = a.x * scale + w0 * lo16(v0.x) + w1 * lo16(v1.x) + w2 * lo16(v2.x) + w3 * lo16(v3.x);
        a.y = a.y * scale + w0 * hi16(v0.x) + w1 * hi16(v1.x) + w2 * hi16(v2.x) + w3 * hi16(v3.x);
        a.z = a.z * scale + w0 * lo16(v0.y) + w1 * lo16(v1.y) + w2 * lo16(v2.y) + w3 * lo16(v3.y);
        a.w = a.w * scale + w0 * hi16(v0.y) + w1 * hi16(v1.y) + w2 * hi16(v2.y) + w3 * hi16(v3.y);
        m = mn;
    }
    for (; p < p1; p++) {
        int s = es[p];
        uint2 kw = *(const uint2*)(k + (long)s * 128 + lane * 4);
        uint2 vw = *(const uint2*)(v + (long)s * 128 + lane * 4);
        float t = q0 * lo16(kw.x) + q1 * hi16(kw.x) + q2 * lo16(kw.y) + q3 * hi16(kw.y);
#pragma unroll
        for (int off = 16; off >= 1; off >>= 1) t += __shfl_xor(t, off, 32);
        t *= SC;
        float mn = fmaxf(m, t);
        float scale = __expf(m - mn);
        float wgt = __expf(t - mn);
        l = l * scale + wgt;
        a.x = a.x * scale + wgt * lo16(vw.x);
        a.y = a.y * scale + wgt * hi16(vw.x);
        a.z = a.z * scale + wgt * lo16(vw.y);
        a.w = a.w * scale + wgt * hi16(vw.y);
        m = mn;
    }
    float invl = (l > 0.f) ? 1.0f / l : 0.f;
    uint2 sw = *(const uint2*)(skip + (long)node * 128 + lane * 4);
    float4 o4;
    o4.x = fmaxf(a.x * invl + lo16(sw.x), 0.f);
    o4.y = fmaxf(a.y * invl + hi16(sw.x), 0.f);
    o4.z = fmaxf(a.z * invl + lo16(sw.y), 0.f);
    o4.w = fmaxf(a.w * invl + hi16(sw.y), 0.f);
    *(float4*)(out + (long)node * 128 + lane * 4) = o4;
}

extern "C" void kernel_launch(void* const* d_in, const int* in_sizes, int n_in,
                              void* d_out, int out_size, void* d_ws, size_t ws_size,
                              hipStream_t stream) {
    const float* x = (const float*)d_in[0];
    const int* ei = (const int*)d_in[1];
    const int* et = (const int*)d_in[2];
    const float* rw = (const float*)d_in[3];
    const float* root = (const float*)d_in[4];
    const float* rbias = (const float*)d_in[5];
    const float* Wq = (const float*)d_in[6];
    const float* bq = (const float*)d_in[7];
    const float* Wk = (const float*)d_in[8];
    const float* bk = (const float*)d_in[9];
    const float* Wv = (const float*)d_in[10];
    const float* bv = (const float*)d_in[11];
    const float* Ws = (const float*)d_in[12];
    const float* bs = (const float*)d_in[13];

    char* ws = (char*)d_ws;
    size_t off = 0;
    auto alloc = [&](size_t b) {
        size_t o = off;
        off = (off + b + 255) & ~(size_t)255;
        return o;
    };
    u16* pre = (u16*)(ws + alloc((size_t)NN * 1152 * 2));
    u16* h = (u16*)(ws + alloc((size_t)NN * 128 * 2));
    u16* qkvs = (u16*)(ws + alloc((size_t)4 * NN * 128 * 2));
    u16* xb = (u16*)(ws + alloc((size_t)NN * 128 * 2));
    u16* wt1 = (u16*)(ws + alloc((size_t)128 * 1152 * 2));
    u16* wt2 = (u16*)(ws + alloc((size_t)4 * 128 * 128 * 2));
    float* bcat = (float*)(ws + alloc((size_t)512 * 4));
    int* cnt = (int*)(ws + alloc((size_t)NN * 8 * 4));
    int* row_off = (int*)(ws + alloc((size_t)(NN + 1) * 4));
    int* srt = (int*)(ws + alloc((size_t)NN * 8 * 4));
    int* deg_pref = (int*)(ws + alloc((size_t)NN * 4));
    int* blk_sums = (int*)(ws + alloc((size_t)128 * 4));
    int* rank = (int*)(ws + alloc((size_t)EE * 4));
    int* es = (int*)(ws + alloc((size_t)EE * 4));
    (void)ws_size;
    (void)in_sizes;
    (void)n_in;
    (void)out_size;

    zero_ints<<<(NN * 8 + 255) / 256, 256, 0, stream>>>(cnt, NN * 8);

    cast_x<<<(NN * 32 + 255) / 256, 256, 0, stream>>>(x, xb);

    prep_weights<<<(128 * 1152 + 4 * 128 * 128 + 512 + 255) / 256, 256, 0, stream>>>(
        rw, root, Wq, Wk, Wv, Ws, bq, bk, bv, bs, wt1, wt2, bcat);

    count_rank<<<EE / 256, 256, 0, stream>>>(ei, et, cnt, rank);
    scan_phase1<<<SCAN_BLOCKS, 256, 0, stream>>>(cnt, deg_pref, blk_sums);
    scan_phase2<<<1, 128, 0, stream>>>(blk_sums);
    scan_phase3<<<SCAN_BLOCKS, 256, 0, stream>>>(cnt, deg_pref, blk_sums, row_off, srt);
    scatter_kernel<<<EE / 256, 256, 0, stream>>>(ei, et, srt, rank, es);

    rgcn_agg<<<(NN + 7) / 8, 256, 0, stream>>>(xb, srt, cnt, es, pre);

    gemm_kernel<<<dim3((NN + 63) / 64, 1), 256, 0, stream>>>(pre, 1152, wt1, 1152, rbias, h, 128,
                                                             NN, 1152, 1, 0, 0, 0);
    gemm_kernel<<<dim3((NN + 63) / 64, 4), 256, 0, stream>>>(h, 128, wt2, 128, bcat, qkvs, 128,
                                                             NN, 128, 0, (long long)128 * 128,
                                                             (long long)NN * 128, 128);

    attn_kernel<<<(NN + 7) / 8, 256, 0, stream>>>(qkvs, qkvs + (size_t)NN * 128, qkvs + (size_t)2 * NN * 128,
                                                  qkvs + (size_t)3 * NN * 128, row_off, es, (float*)d_out);
}

// Round 7
// 254.382 us; speedup vs baseline: 1.3718x; 1.0973x over previous
//
#include <hip/hip_runtime.h>

typedef unsigned short u16;
typedef unsigned int u32;
typedef __attribute__((ext_vector_type(8))) short short8;
typedef __attribute__((ext_vector_type(4))) float f32x4;

#define NN 20000
#define EE 640000
#define SCAN_BLOCKS 80   // 80*256 = 20480 >= NN

__device__ inline u16 f2bf(float f) {
    u32 x = __float_as_uint(f);
    return (u16)((x + 0x7FFFu + ((x >> 16) & 1u)) >> 16);
}
__device__ inline float lo16(u32 w) { return __uint_as_float(w << 16); }
__device__ inline float hi16(u32 w) { return __uint_as_float(w & 0xFFFF0000u); }
__device__ inline u32 packbf(float a, float b) { return ((u32)f2bf(b) << 16) | (u32)f2bf(a); }

// ---------------- fused prep: zero cnt + cast x->bf16 + weight transpose/cast ----------------
#define ZP_N (NN * 8)                                   // 160000 ints to zero
#define CX_N (NN * 32)                                  // 640000 float4s to cast
#define WP_N (128 * 1152 + 4 * 128 * 128 + 512)         // 213504 weight elems
__global__ __launch_bounds__(256) void prep_all(const float* __restrict__ x,
                                                const float* rw, const float* root,
                                                const float* Wq, const float* Wk,
                                                const float* Wv, const float* Ws,
                                                const float* bq, const float* bk,
                                                const float* bv, const float* bs,
                                                int* __restrict__ cnt, u16* __restrict__ xb,
                                                u16* wt1, u16* wt2, float* bcat) {
    int idx = blockIdx.x * 256 + threadIdx.x;
    if (idx < ZP_N) {
        cnt[idx] = 0;
        return;
    }
    idx -= ZP_N;
    if (idx < CX_N) {
        float4 v = *(const float4*)(x + (size_t)idx * 4);
        uint2 o;
        o.x = packbf(v.x, v.y);
        o.y = packbf(v.z, v.w);
        *(uint2*)(xb + (size_t)idx * 4) = o;
        return;
    }
    idx -= CX_N;
    const int S1 = 128 * 1152, S2 = 4 * 128 * 128;
    if (idx < S1) {
        int o = idx / 1152, k = idx - o * 1152;
        float v = (k < 1024) ? rw[k * 128 + o] : root[(k - 1024) * 128 + o];
        wt1[idx] = f2bf(v);
    } else if (idx < S1 + S2) {
        int j = idx - S1;
        int y = j >> 14, rem = j & 16383, o = rem >> 7, i = rem & 127;
        const float* W = (y == 0) ? Wq : (y == 1) ? Wk : (y == 2) ? Wv : Ws;
        wt2[j] = f2bf(W[i * 128 + o]);
    } else if (idx < S1 + S2 + 512) {
        int j = idx - (S1 + S2);
        int y = j >> 7, c = j & 127;
        const float* b = (y == 0) ? bq : (y == 1) ? bk : (y == 2) ? bv : bs;
        bcat[j] = b[c];
    }
}

// ---------------- CSR build: one atomic per edge; returned old value = rank ----------------
__global__ void count_rank(const int* __restrict__ ei, const int* __restrict__ et,
                           int* __restrict__ cnt, int* __restrict__ rank) {
    int e = blockIdx.x * 256 + threadIdx.x;
    if (e >= EE) return;
    int dst = ei[EE + e];
    int r = et[e];
    rank[e] = atomicAdd(&cnt[dst * 8 + r], 1);
}

// ---------------- parallel 3-phase scan ----------------
__global__ __launch_bounds__(256) void scan_phase1(const int* __restrict__ cnt,
                                                   int* __restrict__ deg_pref,
                                                   int* __restrict__ blk_sums) {
    __shared__ int lds[256];
    int t = threadIdx.x;
    int n = blockIdx.x * 256 + t;
    int d = 0;
    if (n < NN) {
        int4 c0 = *(const int4*)(cnt + n * 8);
        int4 c1 = *(const int4*)(cnt + n * 8 + 4);
        d = c0.x + c0.y + c0.z + c0.w + c1.x + c1.y + c1.z + c1.w;
    }
    lds[t] = d;
    __syncthreads();
    for (int o = 1; o < 256; o <<= 1) {
        int v = (t >= o) ? lds[t - o] : 0;
        __syncthreads();
        lds[t] += v;
        __syncthreads();
    }
    if (n < NN) deg_pref[n] = lds[t];
    if (t == 255) blk_sums[blockIdx.x] = lds[255];
}

__global__ void scan_phase2(int* __restrict__ blk_sums) {
    __shared__ int lds[128];
    int t = threadIdx.x;
    int v = (t < SCAN_BLOCKS) ? blk_sums[t] : 0;
    lds[t] = v;
    __syncthreads();
    for (int o = 1; o < 128; o <<= 1) {
        int a = (t >= o) ? lds[t - o] : 0;
        __syncthreads();
        lds[t] += a;
        __syncthreads();
    }
    if (t < SCAN_BLOCKS) blk_sums[t] = lds[t] - v;   // exclusive
}

__global__ __launch_bounds__(256) void scan_phase3(const int* __restrict__ cnt,
                                                   const int* __restrict__ deg_pref,
                                                   const int* __restrict__ blk_sums,
                                                   int* __restrict__ row_off,
                                                   int* __restrict__ srt) {
    int n = blockIdx.x * 256 + threadIdx.x;
    if (n >= NN) return;
    int4 c0 = *(const int4*)(cnt + n * 8);
    int4 c1 = *(const int4*)(cnt + n * 8 + 4);
    int deg = c0.x + c0.y + c0.z + c0.w + c1.x + c1.y + c1.z + c1.w;
    int start = blk_sums[blockIdx.x] + deg_pref[n] - deg;   // exclusive global prefix
    row_off[n] = start;
    int sub = start;
    int o[8];
    o[0] = sub; sub += c0.x;
    o[1] = sub; sub += c0.y;
    o[2] = sub; sub += c0.z;
    o[3] = sub; sub += c0.w;
    o[4] = sub; sub += c1.x;
    o[5] = sub; sub += c1.y;
    o[6] = sub; sub += c1.z;
    o[7] = sub; sub += c1.w;
    *(int4*)(srt + n * 8) = make_int4(o[0], o[1], o[2], o[3]);
    *(int4*)(srt + n * 8 + 4) = make_int4(o[4], o[5], o[6], o[7]);
    if (n == NN - 1) row_off[NN] = sub;
}

// atomic-free scatter using precomputed ranks
__global__ void scatter_kernel(const int* __restrict__ ei, const int* __restrict__ et,
                               const int* __restrict__ srt, const int* __restrict__ rank,
                               int* __restrict__ es) {
    int e = blockIdx.x * 256 + threadIdx.x;
    if (e >= EE) return;
    int dst = ei[EE + e];
    int src = ei[e];
    int r = et[e];
    int pos = srt[dst * 8 + r] + rank[e];
    es[pos] = src;
}

// ---------------- RGCN pre-aggregation: 16-lane group per (node,relation) ----------------
// slot 0..7 = relation mean-aggregate; slot 8 = copy x row into tail (root fused into GEMM)
__global__ __launch_bounds__(256) void rgcn_agg(const u16* __restrict__ xb,
                                                const int* __restrict__ srt,
                                                const int* __restrict__ cnt,
                                                const int* __restrict__ es,
                                                u16* __restrict__ pre) {
    int gid = blockIdx.x * 16 + (threadIdx.x >> 4);
    int lane = threadIdx.x & 15;     // 8 dims/lane
    if (gid >= NN * 9) return;
    int node = gid / 9;
    int slot = gid - node * 9;
    long prebase = (long)node * 1152;
    if (slot == 8) {
        uint4 xv = *(const uint4*)(xb + (long)node * 128 + lane * 8);
        *(uint4*)(pre + prebase + 1024 + lane * 8) = xv;
        return;
    }
    int c = cnt[node * 8 + slot];
    int p0 = srt[node * 8 + slot];
    float inv = 1.0f / (float)(c > 1 ? c : 1);
    float a0 = 0.f, a1 = 0.f, a2 = 0.f, a3 = 0.f, a4 = 0.f, a5 = 0.f, a6 = 0.f, a7 = 0.f;
    int i = 0;
    for (; i + 4 <= c; i += 4) {
        int s0 = es[p0 + i], s1 = es[p0 + i + 1], s2 = es[p0 + i + 2], s3 = es[p0 + i + 3];
        uint4 w0 = *(const uint4*)(xb + (long)s0 * 128 + lane * 8);
        uint4 w1 = *(const uint4*)(xb + (long)s1 * 128 + lane * 8);
        uint4 w2 = *(const uint4*)(xb + (long)s2 * 128 + lane * 8);
        uint4 w3 = *(const uint4*)(xb + (long)s3 * 128 + lane * 8);
        a0 += (lo16(w0.x) + lo16(w1.x)) + (lo16(w2.x) + lo16(w3.x));
        a1 += (hi16(w0.x) + hi16(w1.x)) + (hi16(w2.x) + hi16(w3.x));
        a2 += (lo16(w0.y) + lo16(w1.y)) + (lo16(w2.y) + lo16(w3.y));
        a3 += (hi16(w0.y) + hi16(w1.y)) + (hi16(w2.y) + hi16(w3.y));
        a4 += (lo16(w0.z) + lo16(w1.z)) + (lo16(w2.z) + lo16(w3.z));
        a5 += (hi16(w0.z) + hi16(w1.z)) + (hi16(w2.z) + hi16(w3.z));
        a6 += (lo16(w0.w) + lo16(w1.w)) + (lo16(w2.w) + lo16(w3.w));
        a7 += (hi16(w0.w) + hi16(w1.w)) + (hi16(w2.w) + hi16(w3.w));
    }
    for (; i < c; i++) {
        int s = es[p0 + i];
        uint4 w = *(const uint4*)(xb + (long)s * 128 + lane * 8);
        a0 += lo16(w.x); a1 += hi16(w.x); a2 += lo16(w.y); a3 += hi16(w.y);
        a4 += lo16(w.z); a5 += hi16(w.z); a6 += lo16(w.w); a7 += hi16(w.w);
    }
    uint4 ow;
    ow.x = packbf(a0 * inv, a1 * inv);
    ow.y = packbf(a2 * inv, a3 * inv);
    ow.z = packbf(a4 * inv, a5 * inv);
    ow.w = packbf(a6 * inv, a7 * inv);
    *(uint4*)(pre + prebase + slot * 128 + lane * 8) = ow;
}

// ---------------- MFMA GEMM: C[rows x 128] = A[rows x K] * Bt^T + bias (opt relu) ----------------
__global__ __launch_bounds__(256) void gemm_kernel(const u16* __restrict__ A, int lda,
                                                   const u16* __restrict__ Bt, int ldbt,
                                                   const float* __restrict__ bias,
                                                   u16* __restrict__ C, int ldc,
                                                   int rows, int K, int relu,
                                                   long long yBt, long long yC, long long yBias) {
    Bt += blockIdx.y * yBt;
    C += blockIdx.y * yC;
    bias += blockIdx.y * yBias;
    __shared__ u16 As[64 * 136];
    __shared__ u16 Bs[128 * 136];
    int tid = threadIdx.x;
    int w = tid >> 6;
    int lane = tid & 63;
    int quad = lane >> 4;
    int ml = lane & 15;
    int block_m = blockIdx.x * 64;

    f32x4 acc[8];
#pragma unroll
    for (int i = 0; i < 8; i++) acc[i] = (f32x4){0.f, 0.f, 0.f, 0.f};

    int rbase = tid >> 4;
    int cb = (tid & 15) * 8;

    for (int kb = 0; kb < K; kb += 128) {
#pragma unroll
        for (int rep = 0; rep < 4; rep++) {
            int r = rbase + rep * 16;
            int gr = block_m + r;
            short8 val = {};
            if (gr < rows) val = *(const short8*)(A + (long)gr * lda + kb + cb);
            *(short8*)(As + r * 136 + cb) = val;
        }
#pragma unroll
        for (int rep = 0; rep < 8; rep++) {
            int r = rbase + rep * 16;
            short8 val = *(const short8*)(Bt + (long)r * ldbt + kb + cb);
            *(short8*)(Bs + r * 136 + cb) = val;
        }
        __syncthreads();
#pragma unroll
        for (int ks = 0; ks < 4; ks++) {
            short8 af = *(const short8*)(As + (w * 16 + ml) * 136 + ks * 32 + quad * 8);
#pragma unroll
            for (int nt = 0; nt < 8; nt++) {
                short8 bfr = *(const short8*)(Bs + (nt * 16 + ml) * 136 + ks * 32 + quad * 8);
                acc[nt] = __builtin_amdgcn_mfma_f32_16x16x32_bf16(af, bfr, acc[nt], 0, 0, 0);
            }
        }
        __syncthreads();
    }
#pragma unroll
    for (int nt = 0; nt < 8; nt++) {
        int col = nt * 16 + ml;
        float bv = bias[col];
#pragma unroll
        for (int i = 0; i < 4; i++) {
            int gr = block_m + w * 16 + quad * 4 + i;
            if (gr < rows) {
                float vv = acc[nt][i] + bv;
                if (relu) vv = fmaxf(vv, 0.f);
                C[(long)gr * ldc + col] = f2bf(vv);
            }
        }
    }
}

// ---------------- attention: half-wave per node, 4x edge ILP, online softmax ----------------
__global__ __launch_bounds__(256) void attn_kernel(const u16* __restrict__ q, const u16* __restrict__ k,
                                                   const u16* __restrict__ v, const u16* __restrict__ skip,
                                                   const int* __restrict__ row_off, const int* __restrict__ es,
                                                   float* __restrict__ out) {
    int node = blockIdx.x * 8 + (threadIdx.x >> 5);
    int lane = threadIdx.x & 31;     // 4 dims/lane
    if (node >= NN) return;
    int p0 = row_off[node], p1 = row_off[node + 1];
    uint2 qw = *(const uint2*)(q + (long)node * 128 + lane * 4);
    float q0 = lo16(qw.x), q1 = hi16(qw.x), q2 = lo16(qw.y), q3 = hi16(qw.y);
    const float SC = 0.08838834764831845f;  // 1/sqrt(128)
    float m = -INFINITY, l = 0.f;
    float4 a = {0.f, 0.f, 0.f, 0.f};
    int p = p0;
    for (; p + 4 <= p1; p += 4) {
        int s0 = es[p], s1 = es[p + 1], s2 = es[p + 2], s3 = es[p + 3];
        uint2 k0 = *(const uint2*)(k + (long)s0 * 128 + lane * 4);
        uint2 k1 = *(const uint2*)(k + (long)s1 * 128 + lane * 4);
        uint2 k2 = *(const uint2*)(k + (long)s2 * 128 + lane * 4);
        uint2 k3 = *(const uint2*)(k + (long)s3 * 128 + lane * 4);
        uint2 v0 = *(const uint2*)(v + (long)s0 * 128 + lane * 4);
        uint2 v1 = *(const uint2*)(v + (long)s1 * 128 + lane * 4);
        uint2 v2 = *(const uint2*)(v + (long)s2 * 128 + lane * 4);
        uint2 v3 = *(const uint2*)(v + (long)s3 * 128 + lane * 4);
        float t0 = q0 * lo16(k0.x) + q1 * hi16(k0.x) + q2 * lo16(k0.y) + q3 * hi16(k0.y);
        float t1 = q0 * lo16(k1.x) + q1 * hi16(k1.x) + q2 * lo16(k1.y) + q3 * hi16(k1.y);
        float t2 = q0 * lo16(k2.x) + q1 * hi16(k2.x) + q2 * lo16(k2.y) + q3 * hi16(k2.y);
        float t3 = q0 * lo16(k3.x) + q1 * hi16(k3.x) + q2 * lo16(k3.y) + q3 * hi16(k3.y);
#pragma unroll
        for (int off = 16; off >= 1; off >>= 1) {
            t0 += __shfl_xor(t0, off, 32);
            t1 += __shfl_xor(t1, off, 32);
            t2 += __shfl_xor(t2, off, 32);
            t3 += __shfl_xor(t3, off, 32);
        }
        t0 *= SC; t1 *= SC; t2 *= SC; t3 *= SC;
        float mx = fmaxf(fmaxf(t0, t1), fmaxf(t2, t3));
        float mn = fmaxf(m, mx);
        float scale = __expf(m - mn);
        float w0 = __expf(t0 - mn), w1 = __expf(t1 - mn), w2 = __expf(t2 - mn), w3 = __expf(t3 - mn);
        l = l * scale + ((w0 + w1) + (w2 + w3));
        a.x = a.x * scale + w0 * lo16(v0.x) + w1 * lo16(v1.x) + w2 * lo16(v2.x) + w3 * lo16(v3.x);
        a.y = a.y * scale + w0 * hi16(v0.x) + w1 * hi16(v1.x) + w2 * hi16(v2.x) + w3 * hi16(v3.x);
        a.z = a.z * scale + w0 * lo16(v0.y) + w1 * lo16(v1.y) + w2 * lo16(v2.y) + w3 * lo16(v3.y);
        a.w = a.w * scale + w0 * hi16(v0.y) + w1 * hi16(v1.y) + w2 * hi16(v2.y) + w3 * hi16(v3.y);
        m = mn;
    }
    for (; p < p1; p++) {
        int s = es[p];
        uint2 kw = *(const uint2*)(k + (long)s * 128 + lane * 4);
        uint2 vw = *(const uint2*)(v + (long)s * 128 + lane * 4);
        float t = q0 * lo16(kw.x) + q1 * hi16(kw.x) + q2 * lo16(kw.y) + q3 * hi16(kw.y);
#pragma unroll
        for (int off = 16; off >= 1; off >>= 1) t += __shfl_xor(t, off, 32);
        t *= SC;
        float mn = fmaxf(m, t);
        float scale = __expf(m - mn);
        float wgt = __expf(t - mn);
        l = l * scale + wgt;
        a.x = a.x * scale + wgt * lo16(vw.x);
        a.y = a.y * scale + wgt * hi16(vw.x);
        a.z = a.z * scale + wgt * lo16(vw.y);
        a.w = a.w * scale + wgt * hi16(vw.y);
        m = mn;
    }
    float invl = (l > 0.f) ? 1.0f / l : 0.f;
    uint2 sw = *(const uint2*)(skip + (long)node * 128 + lane * 4);
    float4 o4;
    o4.x = fmaxf(a.x * invl + lo16(sw.x), 0.f);
    o4.y = fmaxf(a.y * invl + hi16(sw.x), 0.f);
    o4.z = fmaxf(a.z * invl + lo16(sw.y), 0.f);
    o4.w = fmaxf(a.w * invl + hi16(sw.y), 0.f);
    *(float4*)(out + (long)node * 128 + lane * 4) = o4;
}

extern "C" void kernel_launch(void* const* d_in, const int* in_sizes, int n_in,
                              void* d_out, int out_size, void* d_ws, size_t ws_size,
                              hipStream_t stream) {
    const float* x = (const float*)d_in[0];
    const int* ei = (const int*)d_in[1];
    const int* et = (const int*)d_in[2];
    const float* rw = (const float*)d_in[3];
    const float* root = (const float*)d_in[4];
    const float* rbias = (const float*)d_in[5];
    const float* Wq = (const float*)d_in[6];
    const float* bq = (const float*)d_in[7];
    const float* Wk = (const float*)d_in[8];
    const float* bk = (const float*)d_in[9];
    const float* Wv = (const float*)d_in[10];
    const float* bv = (const float*)d_in[11];
    const float* Ws = (const float*)d_in[12];
    const float* bs = (const float*)d_in[13];

    char* ws = (char*)d_ws;
    size_t off = 0;
    auto alloc = [&](size_t b) {
        size_t o = off;
        off = (off + b + 255) & ~(size_t)255;
        return o;
    };
    u16* pre = (u16*)(ws + alloc((size_t)NN * 1152 * 2));
    u16* h = (u16*)(ws + alloc((size_t)NN * 128 * 2));
    u16* qkvs = (u16*)(ws + alloc((size_t)4 * NN * 128 * 2));
    u16* xb = (u16*)(ws + alloc((size_t)NN * 128 * 2));
    u16* wt1 = (u16*)(ws + alloc((size_t)128 * 1152 * 2));
    u16* wt2 = (u16*)(ws + alloc((size_t)4 * 128 * 128 * 2));
    float* bcat = (float*)(ws + alloc((size_t)512 * 4));
    int* cnt = (int*)(ws + alloc((size_t)NN * 8 * 4));
    int* row_off = (int*)(ws + alloc((size_t)(NN + 1) * 4));
    int* srt = (int*)(ws + alloc((size_t)NN * 8 * 4));
    int* deg_pref = (int*)(ws + alloc((size_t)NN * 4));
    int* blk_sums = (int*)(ws + alloc((size_t)128 * 4));
    int* rank = (int*)(ws + alloc((size_t)EE * 4));
    int* es = (int*)(ws + alloc((size_t)EE * 4));
    (void)ws_size;
    (void)in_sizes;
    (void)n_in;
    (void)out_size;

    prep_all<<<(ZP_N + CX_N + WP_N + 255) / 256, 256, 0, stream>>>(
        x, rw, root, Wq, Wk, Wv, Ws, bq, bk, bv, bs, cnt, xb, wt1, wt2, bcat);

    count_rank<<<EE / 256, 256, 0, stream>>>(ei, et, cnt, rank);
    scan_phase1<<<SCAN_BLOCKS, 256, 0, stream>>>(cnt, deg_pref, blk_sums);
    scan_phase2<<<1, 128, 0, stream>>>(blk_sums);
    scan_phase3<<<SCAN_BLOCKS, 256, 0, stream>>>(cnt, deg_pref, blk_sums, row_off, srt);
    scatter_kernel<<<EE / 256, 256, 0, stream>>>(ei, et, srt, rank, es);

    rgcn_agg<<<(NN * 9 + 15) / 16, 256, 0, stream>>>(xb, srt, cnt, es, pre);

    gemm_kernel<<<dim3((NN + 63) / 64, 1), 256, 0, stream>>>(pre, 1152, wt1, 1152, rbias, h, 128,
                                                             NN, 1152, 1, 0, 0, 0);
    gemm_kernel<<<dim3((NN + 63) / 64, 4), 256, 0, stream>>>(h, 128, wt2, 128, bcat, qkvs, 128,
                                                             NN, 128, 0, (long long)128 * 128,
                                                             (long long)NN * 128, 128);

    attn_kernel<<<(NN + 7) / 8, 256, 0, stream>>>(qkvs, qkvs + (size_t)NN * 128, qkvs + (size_t)2 * NN * 128,
                                                  qkvs + (size_t)3 * NN * 128, row_off, es, (float*)d_out);
}

// Round 8
// 250.915 us; speedup vs baseline: 1.3907x; 1.0138x over previous
//
#include <hip/hip_runtime.h>

typedef unsigned short u16;
typedef unsigned int u32;
typedef __attribute__((ext_vector_type(8))) short short8;
typedef __attribute__((ext_vector_type(4))) float f32x4;

#define NN 20000
#define EE 640000
#define SCAN_BLOCKS 80   // 80*256 = 20480 >= NN

__device__ inline u16 f2bf(float f) {
    u32 x = __float_as_uint(f);
    return (u16)((x + 0x7FFFu + ((x >> 16) & 1u)) >> 16);
}
__device__ inline float lo16(u32 w) { return __uint_as_float(w << 16); }
__device__ inline float hi16(u32 w) { return __uint_as_float(w & 0xFFFF0000u); }
__device__ inline u32 packbf(float a, float b) { return ((u32)f2bf(b) << 16) | (u32)f2bf(a); }

// ---------------- fused prep: zero cnt + cast x->bf16 + weight transpose/cast ----------------
#define ZP_N (NN * 8)
#define CX_N (NN * 32)
#define WP_N (128 * 1152 + 4 * 128 * 128 + 512)
__global__ __launch_bounds__(256) void prep_all(const float* __restrict__ x,
                                                const float* rw, const float* root,
                                                const float* Wq, const float* Wk,
                                                const float* Wv, const float* Ws,
                                                const float* bq, const float* bk,
                                                const float* bv, const float* bs,
                                                int* __restrict__ cnt, u16* __restrict__ xb,
                                                u16* wt1, u16* wt2, float* bcat) {
    int idx = blockIdx.x * 256 + threadIdx.x;
    if (idx < ZP_N) {
        cnt[idx] = 0;
        return;
    }
    idx -= ZP_N;
    if (idx < CX_N) {
        float4 v = *(const float4*)(x + (size_t)idx * 4);
        uint2 o;
        o.x = packbf(v.x, v.y);
        o.y = packbf(v.z, v.w);
        *(uint2*)(xb + (size_t)idx * 4) = o;
        return;
    }
    idx -= CX_N;
    const int S1 = 128 * 1152, S2 = 4 * 128 * 128;
    if (idx < S1) {
        int o = idx / 1152, k = idx - o * 1152;
        float v = (k < 1024) ? rw[k * 128 + o] : root[(k - 1024) * 128 + o];
        wt1[idx] = f2bf(v);
    } else if (idx < S1 + S2) {
        int j = idx - S1;
        int y = j >> 14, rem = j & 16383, o = rem >> 7, i = rem & 127;
        const float* W = (y == 0) ? Wq : (y == 1) ? Wk : (y == 2) ? Wv : Ws;
        wt2[j] = f2bf(W[i * 128 + o]);
    } else if (idx < S1 + S2 + 512) {
        int j = idx - (S1 + S2);
        int y = j >> 7, c = j & 127;
        const float* b = (y == 0) ? bq : (y == 1) ? bk : (y == 2) ? bv : bs;
        bcat[j] = b[c];
    }
}

// ---------------- CSR build: one atomic per edge, 4 edges/thread ----------------
__global__ void count_rank(const int* __restrict__ ei, const int* __restrict__ et,
                           int* __restrict__ cnt, int* __restrict__ rank) {
    int base = blockIdx.x * 1024 + threadIdx.x;
#pragma unroll
    for (int j = 0; j < 4; j++) {
        int e = base + j * 256;
        if (e < EE) {
            int dst = ei[EE + e];
            int r = et[e];
            rank[e] = atomicAdd(&cnt[dst * 8 + r], 1);
        }
    }
}

// ---------------- parallel 3-phase scan ----------------
__global__ __launch_bounds__(256) void scan_phase1(const int* __restrict__ cnt,
                                                   int* __restrict__ deg_pref,
                                                   int* __restrict__ blk_sums) {
    __shared__ int lds[256];
    int t = threadIdx.x;
    int n = blockIdx.x * 256 + t;
    int d = 0;
    if (n < NN) {
        int4 c0 = *(const int4*)(cnt + n * 8);
        int4 c1 = *(const int4*)(cnt + n * 8 + 4);
        d = c0.x + c0.y + c0.z + c0.w + c1.x + c1.y + c1.z + c1.w;
    }
    lds[t] = d;
    __syncthreads();
    for (int o = 1; o < 256; o <<= 1) {
        int v = (t >= o) ? lds[t - o] : 0;
        __syncthreads();
        lds[t] += v;
        __syncthreads();
    }
    if (n < NN) deg_pref[n] = lds[t];
    if (t == 255) blk_sums[blockIdx.x] = lds[255];
}

__global__ void scan_phase2(int* __restrict__ blk_sums) {
    __shared__ int lds[128];
    int t = threadIdx.x;
    int v = (t < SCAN_BLOCKS) ? blk_sums[t] : 0;
    lds[t] = v;
    __syncthreads();
    for (int o = 1; o < 128; o <<= 1) {
        int a = (t >= o) ? lds[t - o] : 0;
        __syncthreads();
        lds[t] += a;
        __syncthreads();
    }
    if (t < SCAN_BLOCKS) blk_sums[t] = lds[t] - v;   // exclusive
}

__global__ __launch_bounds__(256) void scan_phase3(const int* __restrict__ cnt,
                                                   const int* __restrict__ deg_pref,
                                                   const int* __restrict__ blk_sums,
                                                   int* __restrict__ row_off,
                                                   int* __restrict__ srt) {
    int n = blockIdx.x * 256 + threadIdx.x;
    if (n >= NN) return;
    int4 c0 = *(const int4*)(cnt + n * 8);
    int4 c1 = *(const int4*)(cnt + n * 8 + 4);
    int deg = c0.x + c0.y + c0.z + c0.w + c1.x + c1.y + c1.z + c1.w;
    int start = blk_sums[blockIdx.x] + deg_pref[n] - deg;
    row_off[n] = start;
    int sub = start;
    int o[8];
    o[0] = sub; sub += c0.x;
    o[1] = sub; sub += c0.y;
    o[2] = sub; sub += c0.z;
    o[3] = sub; sub += c0.w;
    o[4] = sub; sub += c1.x;
    o[5] = sub; sub += c1.y;
    o[6] = sub; sub += c1.z;
    o[7] = sub; sub += c1.w;
    *(int4*)(srt + n * 8) = make_int4(o[0], o[1], o[2], o[3]);
    *(int4*)(srt + n * 8 + 4) = make_int4(o[4], o[5], o[6], o[7]);
    if (n == NN - 1) row_off[NN] = sub;
}

// atomic-free scatter, 4 edges/thread
__global__ void scatter_kernel(const int* __restrict__ ei, const int* __restrict__ et,
                               const int* __restrict__ srt, const int* __restrict__ rank,
                               int* __restrict__ es) {
    int base = blockIdx.x * 1024 + threadIdx.x;
#pragma unroll
    for (int j = 0; j < 4; j++) {
        int e = base + j * 256;
        if (e < EE) {
            int dst = ei[EE + e];
            int src = ei[e];
            int r = et[e];
            es[srt[dst * 8 + r] + rank[e]] = src;
        }
    }
}

// ---------------- RGCN pre-aggregation: 16-lane group per (node,relation) ----------------
__global__ __launch_bounds__(256) void rgcn_agg(const u16* __restrict__ xb,
                                                const int* __restrict__ srt,
                                                const int* __restrict__ cnt,
                                                const int* __restrict__ es,
                                                u16* __restrict__ pre) {
    int gid = blockIdx.x * 16 + (threadIdx.x >> 4);
    int lane = threadIdx.x & 15;     // 8 dims/lane
    if (gid >= NN * 9) return;
    int node = gid / 9;
    int slot = gid - node * 9;
    long prebase = (long)node * 1152;
    if (slot == 8) {
        uint4 xv = *(const uint4*)(xb + (long)node * 128 + lane * 8);
        *(uint4*)(pre + prebase + 1024 + lane * 8) = xv;
        return;
    }
    int c = cnt[node * 8 + slot];
    int p0 = srt[node * 8 + slot];
    float inv = 1.0f / (float)(c > 1 ? c : 1);
    float a0 = 0.f, a1 = 0.f, a2 = 0.f, a3 = 0.f, a4 = 0.f, a5 = 0.f, a6 = 0.f, a7 = 0.f;
    int i = 0;
    for (; i + 4 <= c; i += 4) {
        int s0 = es[p0 + i], s1 = es[p0 + i + 1], s2 = es[p0 + i + 2], s3 = es[p0 + i + 3];
        uint4 w0 = *(const uint4*)(xb + (long)s0 * 128 + lane * 8);
        uint4 w1 = *(const uint4*)(xb + (long)s1 * 128 + lane * 8);
        uint4 w2 = *(const uint4*)(xb + (long)s2 * 128 + lane * 8);
        uint4 w3 = *(const uint4*)(xb + (long)s3 * 128 + lane * 8);
        a0 += (lo16(w0.x) + lo16(w1.x)) + (lo16(w2.x) + lo16(w3.x));
        a1 += (hi16(w0.x) + hi16(w1.x)) + (hi16(w2.x) + hi16(w3.x));
        a2 += (lo16(w0.y) + lo16(w1.y)) + (lo16(w2.y) + lo16(w3.y));
        a3 += (hi16(w0.y) + hi16(w1.y)) + (hi16(w2.y) + hi16(w3.y));
        a4 += (lo16(w0.z) + lo16(w1.z)) + (lo16(w2.z) + lo16(w3.z));
        a5 += (hi16(w0.z) + hi16(w1.z)) + (hi16(w2.z) + hi16(w3.z));
        a6 += (lo16(w0.w) + lo16(w1.w)) + (lo16(w2.w) + lo16(w3.w));
        a7 += (hi16(w0.w) + hi16(w1.w)) + (hi16(w2.w) + hi16(w3.w));
    }
    for (; i < c; i++) {
        int s = es[p0 + i];
        uint4 w = *(const uint4*)(xb + (long)s * 128 + lane * 8);
        a0 += lo16(w.x); a1 += hi16(w.x); a2 += lo16(w.y); a3 += hi16(w.y);
        a4 += lo16(w.z); a5 += hi16(w.z); a6 += lo16(w.w); a7 += hi16(w.w);
    }
    uint4 ow;
    ow.x = packbf(a0 * inv, a1 * inv);
    ow.y = packbf(a2 * inv, a3 * inv);
    ow.z = packbf(a4 * inv, a5 * inv);
    ow.w = packbf(a6 * inv, a7 * inv);
    *(uint4*)(pre + prebase + slot * 128 + lane * 8) = ow;
}

// ---------------- GEMM1: BM=32 tiles, K=1152, relu.  C[rows x 128] = A*Bt^T + bias ----------------
__global__ __launch_bounds__(256) void gemm_bm32(const u16* __restrict__ A,
                                                 const u16* __restrict__ Bt,
                                                 const float* __restrict__ bias,
                                                 u16* __restrict__ C, int rows) {
    __shared__ u16 As[32 * 136];
    __shared__ u16 Bs[128 * 136];
    int tid = threadIdx.x;
    int w = tid >> 6;
    int lane = tid & 63;
    int quad = lane >> 4;
    int ml = lane & 15;
    int mt = w & 1;          // m-tile (0..1)
    int nq = w >> 1;         // n-quarter (0..1), 64 cols each
    int block_m = blockIdx.x * 32;

    f32x4 acc[4];
#pragma unroll
    for (int i = 0; i < 4; i++) acc[i] = (f32x4){0.f, 0.f, 0.f, 0.f};

    int rbase = tid >> 4;
    int cb = (tid & 15) * 8;

    for (int kb = 0; kb < 1152; kb += 128) {
#pragma unroll
        for (int rep = 0; rep < 2; rep++) {
            int r = rbase + rep * 16;
            int gr = block_m + r;
            short8 val = {};
            if (gr < rows) val = *(const short8*)(A + (long)gr * 1152 + kb + cb);
            *(short8*)(As + r * 136 + cb) = val;
        }
#pragma unroll
        for (int rep = 0; rep < 8; rep++) {
            int r = rbase + rep * 16;
            short8 val = *(const short8*)(Bt + (long)r * 1152 + kb + cb);
            *(short8*)(Bs + r * 136 + cb) = val;
        }
        __syncthreads();
#pragma unroll
        for (int ks = 0; ks < 4; ks++) {
            short8 af = *(const short8*)(As + (mt * 16 + ml) * 136 + ks * 32 + quad * 8);
#pragma unroll
            for (int nt = 0; nt < 4; nt++) {
                short8 bfr = *(const short8*)(Bs + (nq * 64 + nt * 16 + ml) * 136 + ks * 32 + quad * 8);
                acc[nt] = __builtin_amdgcn_mfma_f32_16x16x32_bf16(af, bfr, acc[nt], 0, 0, 0);
            }
        }
        __syncthreads();
    }
#pragma unroll
    for (int nt = 0; nt < 4; nt++) {
        int col = nq * 64 + nt * 16 + ml;
        float bv = bias[col];
#pragma unroll
        for (int i = 0; i < 4; i++) {
            int gr = block_m + mt * 16 + quad * 4 + i;
            if (gr < rows) {
                float vv = fmaxf(acc[nt][i] + bv, 0.f);
                C[(long)gr * 128 + col] = f2bf(vv);
            }
        }
    }
}

// ---------------- GEMM2 (qkvs): BM=64, K=128 ----------------
__global__ __launch_bounds__(256) void gemm_kernel(const u16* __restrict__ A, int lda,
                                                   const u16* __restrict__ Bt, int ldbt,
                                                   const float* __restrict__ bias,
                                                   u16* __restrict__ C, int ldc,
                                                   int rows, int K, int relu,
                                                   long long yBt, long long yC, long long yBias) {
    Bt += blockIdx.y * yBt;
    C += blockIdx.y * yC;
    bias += blockIdx.y * yBias;
    __shared__ u16 As[64 * 136];
    __shared__ u16 Bs[128 * 136];
    int tid = threadIdx.x;
    int w = tid >> 6;
    int lane = tid & 63;
    int quad = lane >> 4;
    int ml = lane & 15;
    int block_m = blockIdx.x * 64;

    f32x4 acc[8];
#pragma unroll
    for (int i = 0; i < 8; i++) acc[i] = (f32x4){0.f, 0.f, 0.f, 0.f};

    int rbase = tid >> 4;
    int cb = (tid & 15) * 8;

    for (int kb = 0; kb < K; kb += 128) {
#pragma unroll
        for (int rep = 0; rep < 4; rep++) {
            int r = rbase + rep * 16;
            int gr = block_m + r;
            short8 val = {};
            if (gr < rows) val = *(const short8*)(A + (long)gr * lda + kb + cb);
            *(short8*)(As + r * 136 + cb) = val;
        }
#pragma unroll
        for (int rep = 0; rep < 8; rep++) {
            int r = rbase + rep * 16;
            short8 val = *(const short8*)(Bt + (long)r * ldbt + kb + cb);
            *(short8*)(Bs + r * 136 + cb) = val;
        }
        __syncthreads();
#pragma unroll
        for (int ks = 0; ks < 4; ks++) {
            short8 af = *(const short8*)(As + (w * 16 + ml) * 136 + ks * 32 + quad * 8);
#pragma unroll
            for (int nt = 0; nt < 8; nt++) {
                short8 bfr = *(const short8*)(Bs + (nt * 16 + ml) * 136 + ks * 32 + quad * 8);
                acc[nt] = __builtin_amdgcn_mfma_f32_16x16x32_bf16(af, bfr, acc[nt], 0, 0, 0);
            }
        }
        __syncthreads();
    }
#pragma unroll
    for (int nt = 0; nt < 8; nt++) {
        int col = nt * 16 + ml;
        float bv = bias[col];
#pragma unroll
        for (int i = 0; i < 4; i++) {
            int gr = block_m + w * 16 + quad * 4 + i;
            if (gr < rows) {
                float vv = acc[nt][i] + bv;
                if (relu) vv = fmaxf(vv, 0.f);
                C[(long)gr * ldc + col] = f2bf(vv);
            }
        }
    }
}

// ---------------- attention: 16-lane group per node, 4x edge ILP, online softmax ----------------
__global__ __launch_bounds__(256) void attn_kernel(const u16* __restrict__ q, const u16* __restrict__ k,
                                                   const u16* __restrict__ v, const u16* __restrict__ skip,
                                                   const int* __restrict__ row_off, const int* __restrict__ es,
                                                   float* __restrict__ out) {
    int node = blockIdx.x * 16 + (threadIdx.x >> 4);
    int lane = threadIdx.x & 15;     // 8 dims/lane
    if (node >= NN) return;
    int p0 = row_off[node], p1 = row_off[node + 1];
    uint4 qw = *(const uint4*)(q + (long)node * 128 + lane * 8);
    float q0 = lo16(qw.x), q1 = hi16(qw.x), q2 = lo16(qw.y), q3 = hi16(qw.y);
    float q4 = lo16(qw.z), q5 = hi16(qw.z), q6 = lo16(qw.w), q7 = hi16(qw.w);
    const float SC = 0.08838834764831845f;  // 1/sqrt(128)
    float m = -INFINITY, l = 0.f;
    float a0 = 0.f, a1 = 0.f, a2 = 0.f, a3 = 0.f, a4 = 0.f, a5 = 0.f, a6 = 0.f, a7 = 0.f;
    int p = p0;
    for (; p + 4 <= p1; p += 4) {
        int s0 = es[p], s1 = es[p + 1], s2 = es[p + 2], s3 = es[p + 3];
        uint4 k0 = *(const uint4*)(k + (long)s0 * 128 + lane * 8);
        uint4 k1 = *(const uint4*)(k + (long)s1 * 128 + lane * 8);
        uint4 k2 = *(const uint4*)(k + (long)s2 * 128 + lane * 8);
        uint4 k3 = *(const uint4*)(k + (long)s3 * 128 + lane * 8);
        uint4 v0 = *(const uint4*)(v + (long)s0 * 128 + lane * 8);
        uint4 v1 = *(const uint4*)(v + (long)s1 * 128 + lane * 8);
        uint4 v2 = *(const uint4*)(v + (long)s2 * 128 + lane * 8);
        uint4 v3 = *(const uint4*)(v + (long)s3 * 128 + lane * 8);
        float t0 = q0 * lo16(k0.x) + q1 * hi16(k0.x) + q2 * lo16(k0.y) + q3 * hi16(k0.y) +
                   q4 * lo16(k0.z) + q5 * hi16(k0.z) + q6 * lo16(k0.w) + q7 * hi16(k0.w);
        float t1 = q0 * lo16(k1.x) + q1 * hi16(k1.x) + q2 * lo16(k1.y) + q3 * hi16(k1.y) +
                   q4 * lo16(k1.z) + q5 * hi16(k1.z) + q6 * lo16(k1.w) + q7 * hi16(k1.w);
        float t2 = q0 * lo16(k2.x) + q1 * hi16(k2.x) + q2 * lo16(k2.y) + q3 * hi16(k2.y) +
                   q4 * lo16(k2.z) + q5 * hi16(k2.z) + q6 * lo16(k2.w) + q7 * hi16(k2.w);
        float t3 = q0 * lo16(k3.x) + q1 * hi16(k3.x) + q2 * lo16(k3.y) + q3 * hi16(k3.y) +
                   q4 * lo16(k3.z) + q5 * hi16(k3.z) + q6 * lo16(k3.w) + q7 * hi16(k3.w);
#pragma unroll
        for (int off = 8; off >= 1; off >>= 1) {
            t0 += __shfl_xor(t0, off, 16);
            t1 += __shfl_xor(t1, off, 16);
            t2 += __shfl_xor(t2, off, 16);
            t3 += __shfl_xor(t3, off, 16);
        }
        t0 *= SC; t1 *= SC; t2 *= SC; t3 *= SC;
        float mx = fmaxf(fmaxf(t0, t1), fmaxf(t2, t3));
        float mn = fmaxf(m, mx);
        float scale = __expf(m - mn);
        float w0 = __expf(t0 - mn), w1 = __expf(t1 - mn), w2 = __expf(t2 - mn), w3 = __expf(t3 - mn);
        l = l * scale + ((w0 + w1) + (w2 + w3));
        a0 = a0 * scale + w0 * lo16(v0.x) + w1 * lo16(v1.x) + w2 * lo16(v2.x) + w3 * lo16(v3.x);
        a1 = a1 * scale + w0 * hi16(v0.x) + w1 * hi16(v1.x) + w2 * hi16(v2.x) + w3 * hi16(v3.x);
        a2 = a2 * scale + w0 * lo16(v0.y) + w1 * lo16(v1.y) + w2 * lo16(v2.y) + w3 * lo16(v3.y);
        a3 = a3 * scale + w0 * hi16(v0.y) + w1 * hi16(v1.y) + w2 * hi16(v2.y) + w3 * hi16(v3.y);
        a4 = a4 * scale + w0 * lo16(v0.z) + w1 * lo16(v1.z) + w2 * lo16(v2.z) + w3 * lo16(v3.z);
        a5 = a5 * scale + w0 * hi16(v0.z) + w1 * hi16(v1.z) + w2 * hi16(v2.z) + w3 * hi16(v3.z);
        a6 = a6 * scale + w0 * lo16(v0.w) + w1 * lo16(v1.w) + w2 * lo16(v2.w) + w3 * lo16(v3.w);
        a7 = a7 * scale + w0 * hi16(v0.w) + w1 * hi16(v1.w) + w2 * hi16(v2.w) + w3 * hi16(v3.w);
        m = mn;
    }
    for (; p < p1; p++) {
        int s = es[p];
        uint4 kw = *(const uint4*)(k + (long)s * 128 + lane * 8);
        uint4 vw = *(const uint4*)(v + (long)s * 128 + lane * 8);
        float t = q0 * lo16(kw.x) + q1 * hi16(kw.x) + q2 * lo16(kw.y) + q3 * hi16(kw.y) +
                  q4 * lo16(kw.z) + q5 * hi16(kw.z) + q6 * lo16(kw.w) + q7 * hi16(kw.w);
#pragma unroll
        for (int off = 8; off >= 1; off >>= 1) t += __shfl_xor(t, off, 16);
        t *= SC;
        float mn = fmaxf(m, t);
        float scale = __expf(m - mn);
        float wgt = __expf(t - mn);
        l = l * scale + wgt;
        a0 = a0 * scale + wgt * lo16(vw.x);
        a1 = a1 * scale + wgt * hi16(vw.x);
        a2 = a2 * scale + wgt * lo16(vw.y);
        a3 = a3 * scale + wgt * hi16(vw.y);
        a4 = a4 * scale + wgt * lo16(vw.z);
        a5 = a5 * scale + wgt * hi16(vw.z);
        a6 = a6 * scale + wgt * lo16(vw.w);
        a7 = a7 * scale + wgt * hi16(vw.w);
        m = mn;
    }
    float invl = (l > 0.f) ? 1.0f / l : 0.f;
    uint4 sw = *(const uint4*)(skip + (long)node * 128 + lane * 8);
    float4 oa, ob;
    oa.x = fmaxf(a0 * invl + lo16(sw.x), 0.f);
    oa.y = fmaxf(a1 * invl + hi16(sw.x), 0.f);
    oa.z = fmaxf(a2 * invl + lo16(sw.y), 0.f);
    oa.w = fmaxf(a3 * invl + hi16(sw.y), 0.f);
    ob.x = fmaxf(a4 * invl + lo16(sw.z), 0.f);
    ob.y = fmaxf(a5 * invl + hi16(sw.z), 0.f);
    ob.z = fmaxf(a6 * invl + lo16(sw.w), 0.f);
    ob.w = fmaxf(a7 * invl + hi16(sw.w), 0.f);
    *(float4*)(out + (long)node * 128 + lane * 8) = oa;
    *(float4*)(out + (long)node * 128 + lane * 8 + 4) = ob;
}

extern "C" void kernel_launch(void* const* d_in, const int* in_sizes, int n_in,
                              void* d_out, int out_size, void* d_ws, size_t ws_size,
                              hipStream_t stream) {
    const float* x = (const float*)d_in[0];
    const int* ei = (const int*)d_in[1];
    const int* et = (const int*)d_in[2];
    const float* rw = (const float*)d_in[3];
    const float* root = (const float*)d_in[4];
    const float* rbias = (const float*)d_in[5];
    const float* Wq = (const float*)d_in[6];
    const float* bq = (const float*)d_in[7];
    const float* Wk = (const float*)d_in[8];
    const float* bk = (const float*)d_in[9];
    const float* Wv = (const float*)d_in[10];
    const float* bv = (const float*)d_in[11];
    const float* Ws = (const float*)d_in[12];
    const float* bs = (const float*)d_in[13];

    char* ws = (char*)d_ws;
    size_t off = 0;
    auto alloc = [&](size_t b) {
        size_t o = off;
        off = (off + b + 255) & ~(size_t)255;
        return o;
    };
    u16* pre = (u16*)(ws + alloc((size_t)NN * 1152 * 2));
    u16* h = (u16*)(ws + alloc((size_t)NN * 128 * 2));
    u16* qkvs = (u16*)(ws + alloc((size_t)4 * NN * 128 * 2));
    u16* xb = (u16*)(ws + alloc((size_t)NN * 128 * 2));
    u16* wt1 = (u16*)(ws + alloc((size_t)128 * 1152 * 2));
    u16* wt2 = (u16*)(ws + alloc((size_t)4 * 128 * 128 * 2));
    float* bcat = (float*)(ws + alloc((size_t)512 * 4));
    int* cnt = (int*)(ws + alloc((size_t)NN * 8 * 4));
    int* row_off = (int*)(ws + alloc((size_t)(NN + 1) * 4));
    int* srt = (int*)(ws + alloc((size_t)NN * 8 * 4));
    int* deg_pref = (int*)(ws + alloc((size_t)NN * 4));
    int* blk_sums = (int*)(ws + alloc((size_t)128 * 4));
    int* rank = (int*)(ws + alloc((size_t)EE * 4));
    int* es = (int*)(ws + alloc((size_t)EE * 4));
    (void)ws_size;
    (void)in_sizes;
    (void)n_in;
    (void)out_size;

    prep_all<<<(ZP_N + CX_N + WP_N + 255) / 256, 256, 0, stream>>>(
        x, rw, root, Wq, Wk, Wv, Ws, bq, bk, bv, bs, cnt, xb, wt1, wt2, bcat);

    count_rank<<<(EE + 1023) / 1024, 256, 0, stream>>>(ei, et, cnt, rank);
    scan_phase1<<<SCAN_BLOCKS, 256, 0, stream>>>(cnt, deg_pref, blk_sums);
    scan_phase2<<<1, 128, 0, stream>>>(blk_sums);
    scan_phase3<<<SCAN_BLOCKS, 256, 0, stream>>>(cnt, deg_pref, blk_sums, row_off, srt);
    scatter_kernel<<<(EE + 1023) / 1024, 256, 0, stream>>>(ei, et, srt, rank, es);

    rgcn_agg<<<(NN * 9 + 15) / 16, 256, 0, stream>>>(xb, srt, cnt, es, pre);

    gemm_bm32<<<(NN + 31) / 32, 256, 0, stream>>>(pre, wt1, rbias, h, NN);
    gemm_kernel<<<dim3((NN + 63) / 64, 4), 256, 0, stream>>>(h, 128, wt2, 128, bcat, qkvs, 128,
                                                             NN, 128, 0, (long long)128 * 128,
                                                             (long long)NN * 128, 128);

    attn_kernel<<<(NN + 15) / 16, 256, 0, stream>>>(qkvs, qkvs + (size_t)NN * 128, qkvs + (size_t)2 * NN * 128,
                                                    qkvs + (size_t)3 * NN * 128, row_off, es, (float*)d_out);
}

// Round 9
// 246.083 us; speedup vs baseline: 1.4180x; 1.0196x over previous
//
#include <hip/hip_runtime.h>

typedef unsigned short u16;
typedef unsigned int u32;
typedef __attribute__((ext_vector_type(8))) short short8;
typedef __attribute__((ext_vector_type(4))) float f32x4;

#define NN 20000
#define EE 640000
#define SCAN_BLOCKS 80   // 80*256 = 20480 >= NN

__device__ inline u16 f2bf(float f) {
    u32 x = __float_as_uint(f);
    return (u16)((x + 0x7FFFu + ((x >> 16) & 1u)) >> 16);
}
__device__ inline float lo16(u32 w) { return __uint_as_float(w << 16); }
__device__ inline float hi16(u32 w) { return __uint_as_float(w & 0xFFFF0000u); }
__device__ inline u32 packbf(float a, float b) { return ((u32)f2bf(b) << 16) | (u32)f2bf(a); }

// ---------------- fused prep: zero cnt + cast x->bf16 + weight transpose/cast ----------------
#define ZP_N (NN * 8)
#define CX_N (NN * 32)
#define WP_N (128 * 1152 + 4 * 128 * 128 + 512)
__global__ __launch_bounds__(256) void prep_all(const float* __restrict__ x,
                                                const float* rw, const float* root,
                                                const float* Wq, const float* Wk,
                                                const float* Wv, const float* Ws,
                                                const float* bq, const float* bk,
                                                const float* bv, const float* bs,
                                                int* __restrict__ cnt, u16* __restrict__ xb,
                                                u16* wt1, u16* wt2, float* bcat) {
    int idx = blockIdx.x * 256 + threadIdx.x;
    if (idx < ZP_N) {
        cnt[idx] = 0;
        return;
    }
    idx -= ZP_N;
    if (idx < CX_N) {
        float4 v = *(const float4*)(x + (size_t)idx * 4);
        uint2 o;
        o.x = packbf(v.x, v.y);
        o.y = packbf(v.z, v.w);
        *(uint2*)(xb + (size_t)idx * 4) = o;
        return;
    }
    idx -= CX_N;
    const int S1 = 128 * 1152, S2 = 4 * 128 * 128;
    if (idx < S1) {
        int o = idx / 1152, k = idx - o * 1152;
        float v = (k < 1024) ? rw[k * 128 + o] : root[(k - 1024) * 128 + o];
        wt1[idx] = f2bf(v);
    } else if (idx < S1 + S2) {
        int j = idx - S1;
        int y = j >> 14, rem = j & 16383, o = rem >> 7, i = rem & 127;
        const float* W = (y == 0) ? Wq : (y == 1) ? Wk : (y == 2) ? Wv : Ws;
        wt2[j] = f2bf(W[i * 128 + o]);
    } else if (idx < S1 + S2 + 512) {
        int j = idx - (S1 + S2);
        int y = j >> 7, c = j & 127;
        const float* b = (y == 0) ? bq : (y == 1) ? bk : (y == 2) ? bv : bs;
        bcat[j] = b[c];
    }
}

// ---------------- CSR build: one atomic per edge, 4 edges/thread ----------------
__global__ void count_rank(const int* __restrict__ ei, const int* __restrict__ et,
                           int* __restrict__ cnt, int* __restrict__ rank) {
    int base = blockIdx.x * 1024 + threadIdx.x;
#pragma unroll
    for (int j = 0; j < 4; j++) {
        int e = base + j * 256;
        if (e < EE) {
            int dst = ei[EE + e];
            int r = et[e];
            rank[e] = atomicAdd(&cnt[dst * 8 + r], 1);
        }
    }
}

// ---------------- parallel 3-phase scan ----------------
__global__ __launch_bounds__(256) void scan_phase1(const int* __restrict__ cnt,
                                                   int* __restrict__ deg_pref,
                                                   int* __restrict__ blk_sums) {
    __shared__ int lds[256];
    int t = threadIdx.x;
    int n = blockIdx.x * 256 + t;
    int d = 0;
    if (n < NN) {
        int4 c0 = *(const int4*)(cnt + n * 8);
        int4 c1 = *(const int4*)(cnt + n * 8 + 4);
        d = c0.x + c0.y + c0.z + c0.w + c1.x + c1.y + c1.z + c1.w;
    }
    lds[t] = d;
    __syncthreads();
    for (int o = 1; o < 256; o <<= 1) {
        int v = (t >= o) ? lds[t - o] : 0;
        __syncthreads();
        lds[t] += v;
        __syncthreads();
    }
    if (n < NN) deg_pref[n] = lds[t];
    if (t == 255) blk_sums[blockIdx.x] = lds[255];
}

__global__ void scan_phase2(int* __restrict__ blk_sums) {
    __shared__ int lds[128];
    int t = threadIdx.x;
    int v = (t < SCAN_BLOCKS) ? blk_sums[t] : 0;
    lds[t] = v;
    __syncthreads();
    for (int o = 1; o < 128; o <<= 1) {
        int a = (t >= o) ? lds[t - o] : 0;
        __syncthreads();
        lds[t] += a;
        __syncthreads();
    }
    if (t < SCAN_BLOCKS) blk_sums[t] = lds[t] - v;   // exclusive
}

__global__ __launch_bounds__(256) void scan_phase3(const int* __restrict__ cnt,
                                                   const int* __restrict__ deg_pref,
                                                   const int* __restrict__ blk_sums,
                                                   int* __restrict__ row_off,
                                                   int* __restrict__ srt) {
    int n = blockIdx.x * 256 + threadIdx.x;
    if (n >= NN) return;
    int4 c0 = *(const int4*)(cnt + n * 8);
    int4 c1 = *(const int4*)(cnt + n * 8 + 4);
    int deg = c0.x + c0.y + c0.z + c0.w + c1.x + c1.y + c1.z + c1.w;
    int start = blk_sums[blockIdx.x] + deg_pref[n] - deg;
    row_off[n] = start;
    int sub = start;
    int o[8];
    o[0] = sub; sub += c0.x;
    o[1] = sub; sub += c0.y;
    o[2] = sub; sub += c0.z;
    o[3] = sub; sub += c0.w;
    o[4] = sub; sub += c1.x;
    o[5] = sub; sub += c1.y;
    o[6] = sub; sub += c1.z;
    o[7] = sub; sub += c1.w;
    *(int4*)(srt + n * 8) = make_int4(o[0], o[1], o[2], o[3]);
    *(int4*)(srt + n * 8 + 4) = make_int4(o[4], o[5], o[6], o[7]);
    if (n == NN - 1) row_off[NN] = sub;
}

// atomic-free scatter, 4 edges/thread
__global__ void scatter_kernel(const int* __restrict__ ei, const int* __restrict__ et,
                               const int* __restrict__ srt, const int* __restrict__ rank,
                               int* __restrict__ es) {
    int base = blockIdx.x * 1024 + threadIdx.x;
#pragma unroll
    for (int j = 0; j < 4; j++) {
        int e = base + j * 256;
        if (e < EE) {
            int dst = ei[EE + e];
            int src = ei[e];
            int r = et[e];
            es[srt[dst * 8 + r] + rank[e]] = src;
        }
    }
}

// ---------------- RGCN pre-aggregation: 16-lane group per (node,relation) ----------------
__global__ __launch_bounds__(256) void rgcn_agg(const u16* __restrict__ xb,
                                                const int* __restrict__ srt,
                                                const int* __restrict__ cnt,
                                                const int* __restrict__ es,
                                                u16* __restrict__ pre) {
    int gid = blockIdx.x * 16 + (threadIdx.x >> 4);
    int lane = threadIdx.x & 15;     // 8 dims/lane
    if (gid >= NN * 9) return;
    int node = gid / 9;
    int slot = gid - node * 9;
    long prebase = (long)node * 1152;
    if (slot == 8) {
        uint4 xv = *(const uint4*)(xb + (long)node * 128 + lane * 8);
        *(uint4*)(pre + prebase + 1024 + lane * 8) = xv;
        return;
    }
    int c = cnt[node * 8 + slot];
    int p0 = srt[node * 8 + slot];
    float inv = 1.0f / (float)(c > 1 ? c : 1);
    float a0 = 0.f, a1 = 0.f, a2 = 0.f, a3 = 0.f, a4 = 0.f, a5 = 0.f, a6 = 0.f, a7 = 0.f;
    int i = 0;
    for (; i + 4 <= c; i += 4) {
        int s0 = es[p0 + i], s1 = es[p0 + i + 1], s2 = es[p0 + i + 2], s3 = es[p0 + i + 3];
        uint4 w0 = *(const uint4*)(xb + (long)s0 * 128 + lane * 8);
        uint4 w1 = *(const uint4*)(xb + (long)s1 * 128 + lane * 8);
        uint4 w2 = *(const uint4*)(xb + (long)s2 * 128 + lane * 8);
        uint4 w3 = *(const uint4*)(xb + (long)s3 * 128 + lane * 8);
        a0 += (lo16(w0.x) + lo16(w1.x)) + (lo16(w2.x) + lo16(w3.x));
        a1 += (hi16(w0.x) + hi16(w1.x)) + (hi16(w2.x) + hi16(w3.x));
        a2 += (lo16(w0.y) + lo16(w1.y)) + (lo16(w2.y) + lo16(w3.y));
        a3 += (hi16(w0.y) + hi16(w1.y)) + (hi16(w2.y) + hi16(w3.y));
        a4 += (lo16(w0.z) + lo16(w1.z)) + (lo16(w2.z) + lo16(w3.z));
        a5 += (hi16(w0.z) + hi16(w1.z)) + (hi16(w2.z) + hi16(w3.z));
        a6 += (lo16(w0.w) + lo16(w1.w)) + (lo16(w2.w) + lo16(w3.w));
        a7 += (hi16(w0.w) + hi16(w1.w)) + (hi16(w2.w) + hi16(w3.w));
    }
    for (; i < c; i++) {
        int s = es[p0 + i];
        uint4 w = *(const uint4*)(xb + (long)s * 128 + lane * 8);
        a0 += lo16(w.x); a1 += hi16(w.x); a2 += lo16(w.y); a3 += hi16(w.y);
        a4 += lo16(w.z); a5 += hi16(w.z); a6 += lo16(w.w); a7 += hi16(w.w);
    }
    uint4 ow;
    ow.x = packbf(a0 * inv, a1 * inv);
    ow.y = packbf(a2 * inv, a3 * inv);
    ow.z = packbf(a4 * inv, a5 * inv);
    ow.w = packbf(a6 * inv, a7 * inv);
    *(uint4*)(pre + prebase + slot * 128 + lane * 8) = ow;
}

// ---------------- GEMM1: BM=32 tiles, K=1152, relu.  C[rows x 128] = A*Bt^T + bias ----------------
__global__ __launch_bounds__(256) void gemm_bm32(const u16* __restrict__ A,
                                                 const u16* __restrict__ Bt,
                                                 const float* __restrict__ bias,
                                                 u16* __restrict__ C, int rows) {
    __shared__ u16 As[32 * 136];
    __shared__ u16 Bs[128 * 136];
    int tid = threadIdx.x;
    int w = tid >> 6;
    int lane = tid & 63;
    int quad = lane >> 4;
    int ml = lane & 15;
    int mt = w & 1;
    int nq = w >> 1;
    int block_m = blockIdx.x * 32;

    f32x4 acc[4];
#pragma unroll
    for (int i = 0; i < 4; i++) acc[i] = (f32x4){0.f, 0.f, 0.f, 0.f};

    int rbase = tid >> 4;
    int cb = (tid & 15) * 8;

    for (int kb = 0; kb < 1152; kb += 128) {
#pragma unroll
        for (int rep = 0; rep < 2; rep++) {
            int r = rbase + rep * 16;
            int gr = block_m + r;
            short8 val = {};
            if (gr < rows) val = *(const short8*)(A + (long)gr * 1152 + kb + cb);
            *(short8*)(As + r * 136 + cb) = val;
        }
#pragma unroll
        for (int rep = 0; rep < 8; rep++) {
            int r = rbase + rep * 16;
            short8 val = *(const short8*)(Bt + (long)r * 1152 + kb + cb);
            *(short8*)(Bs + r * 136 + cb) = val;
        }
        __syncthreads();
#pragma unroll
        for (int ks = 0; ks < 4; ks++) {
            short8 af = *(const short8*)(As + (mt * 16 + ml) * 136 + ks * 32 + quad * 8);
#pragma unroll
            for (int nt = 0; nt < 4; nt++) {
                short8 bfr = *(const short8*)(Bs + (nq * 64 + nt * 16 + ml) * 136 + ks * 32 + quad * 8);
                acc[nt] = __builtin_amdgcn_mfma_f32_16x16x32_bf16(af, bfr, acc[nt], 0, 0, 0);
            }
        }
        __syncthreads();
    }
#pragma unroll
    for (int nt = 0; nt < 4; nt++) {
        int col = nq * 64 + nt * 16 + ml;
        float bv = bias[col];
#pragma unroll
        for (int i = 0; i < 4; i++) {
            int gr = block_m + mt * 16 + quad * 4 + i;
            if (gr < rows) {
                float vv = fmaxf(acc[nt][i] + bv, 0.f);
                C[(long)gr * 128 + col] = f2bf(vv);
            }
        }
    }
}

// ---------------- GEMM2 (q / kv-interleaved / skip): BM=64, K=128 ----------------
// y=0 -> q (ldc 128); y=1 -> kv+0 (ldc 256); y=2 -> kv+128 (ldc 256); y=3 -> skip (ldc 128)
__global__ __launch_bounds__(256) void gemm_qkvs(const u16* __restrict__ A,
                                                 const u16* __restrict__ Bt,
                                                 const float* __restrict__ bias,
                                                 u16* __restrict__ Cq, u16* __restrict__ Ckv,
                                                 u16* __restrict__ Cs, int rows) {
    int y = blockIdx.y;
    Bt += (long)y * 128 * 128;
    bias += y * 128;
    u16* C;
    int ldc;
    if (y == 0) { C = Cq; ldc = 128; }
    else if (y == 1) { C = Ckv; ldc = 256; }
    else if (y == 2) { C = Ckv + 128; ldc = 256; }
    else { C = Cs; ldc = 128; }

    __shared__ u16 As[64 * 136];
    __shared__ u16 Bs[128 * 136];
    int tid = threadIdx.x;
    int w = tid >> 6;
    int lane = tid & 63;
    int quad = lane >> 4;
    int ml = lane & 15;
    int block_m = blockIdx.x * 64;

    f32x4 acc[8];
#pragma unroll
    for (int i = 0; i < 8; i++) acc[i] = (f32x4){0.f, 0.f, 0.f, 0.f};

    int rbase = tid >> 4;
    int cb = (tid & 15) * 8;

#pragma unroll
    for (int rep = 0; rep < 4; rep++) {
        int r = rbase + rep * 16;
        int gr = block_m + r;
        short8 val = {};
        if (gr < rows) val = *(const short8*)(A + (long)gr * 128 + cb);
        *(short8*)(As + r * 136 + cb) = val;
    }
#pragma unroll
    for (int rep = 0; rep < 8; rep++) {
        int r = rbase + rep * 16;
        short8 val = *(const short8*)(Bt + (long)r * 128 + cb);
        *(short8*)(Bs + r * 136 + cb) = val;
    }
    __syncthreads();
#pragma unroll
    for (int ks = 0; ks < 4; ks++) {
        short8 af = *(const short8*)(As + (w * 16 + ml) * 136 + ks * 32 + quad * 8);
#pragma unroll
        for (int nt = 0; nt < 8; nt++) {
            short8 bfr = *(const short8*)(Bs + (nt * 16 + ml) * 136 + ks * 32 + quad * 8);
            acc[nt] = __builtin_amdgcn_mfma_f32_16x16x32_bf16(af, bfr, acc[nt], 0, 0, 0);
        }
    }
#pragma unroll
    for (int nt = 0; nt < 8; nt++) {
        int col = nt * 16 + ml;
        float bv = bias[col];
#pragma unroll
        for (int i = 0; i < 4; i++) {
            int gr = block_m + w * 16 + quad * 4 + i;
            if (gr < rows) {
                C[(long)gr * ldc + col] = f2bf(acc[nt][i] + bv);
            }
        }
    }
}

// ---------------- attention: 16-lane/node, direct-exp softmax (no max chain), fused KV ----------------
__global__ __launch_bounds__(256) void attn_kernel(const u16* __restrict__ q,
                                                   const u16* __restrict__ kv,
                                                   const u16* __restrict__ skip,
                                                   const int* __restrict__ row_off,
                                                   const int* __restrict__ es,
                                                   float* __restrict__ out) {
    int node = blockIdx.x * 16 + (threadIdx.x >> 4);
    int lane = threadIdx.x & 15;     // 8 dims/lane
    if (node >= NN) return;
    int p0 = row_off[node], p1 = row_off[node + 1];
    uint4 qw = *(const uint4*)(q + (long)node * 128 + lane * 8);
    float q0 = lo16(qw.x), q1 = hi16(qw.x), q2 = lo16(qw.y), q3 = hi16(qw.y);
    float q4 = lo16(qw.z), q5 = hi16(qw.z), q6 = lo16(qw.w), q7 = hi16(qw.w);
    const float SC = 0.08838834764831845f;  // 1/sqrt(128)
    float l = 0.f;
    float a0 = 0.f, a1 = 0.f, a2 = 0.f, a3 = 0.f, a4 = 0.f, a5 = 0.f, a6 = 0.f, a7 = 0.f;
    int p = p0;
    for (; p + 4 <= p1; p += 4) {
        const u16* b0 = kv + (long)es[p] * 256 + lane * 8;
        const u16* b1 = kv + (long)es[p + 1] * 256 + lane * 8;
        const u16* b2 = kv + (long)es[p + 2] * 256 + lane * 8;
        const u16* b3 = kv + (long)es[p + 3] * 256 + lane * 8;
        uint4 k0 = *(const uint4*)b0;
        uint4 k1 = *(const uint4*)b1;
        uint4 k2 = *(const uint4*)b2;
        uint4 k3 = *(const uint4*)b3;
        uint4 v0 = *(const uint4*)(b0 + 128);
        uint4 v1 = *(const uint4*)(b1 + 128);
        uint4 v2 = *(const uint4*)(b2 + 128);
        uint4 v3 = *(const uint4*)(b3 + 128);
        float t0 = q0 * lo16(k0.x) + q1 * hi16(k0.x) + q2 * lo16(k0.y) + q3 * hi16(k0.y) +
                   q4 * lo16(k0.z) + q5 * hi16(k0.z) + q6 * lo16(k0.w) + q7 * hi16(k0.w);
        float t1 = q0 * lo16(k1.x) + q1 * hi16(k1.x) + q2 * lo16(k1.y) + q3 * hi16(k1.y) +
                   q4 * lo16(k1.z) + q5 * hi16(k1.z) + q6 * lo16(k1.w) + q7 * hi16(k1.w);
        float t2 = q0 * lo16(k2.x) + q1 * hi16(k2.x) + q2 * lo16(k2.y) + q3 * hi16(k2.y) +
                   q4 * lo16(k2.z) + q5 * hi16(k2.z) + q6 * lo16(k2.w) + q7 * hi16(k2.w);
        float t3 = q0 * lo16(k3.x) + q1 * hi16(k3.x) + q2 * lo16(k3.y) + q3 * hi16(k3.y) +
                   q4 * lo16(k3.z) + q5 * hi16(k3.z) + q6 * lo16(k3.w) + q7 * hi16(k3.w);
#pragma unroll
        for (int off = 8; off >= 1; off >>= 1) {
            t0 += __shfl_xor(t0, off, 16);
            t1 += __shfl_xor(t1, off, 16);
            t2 += __shfl_xor(t2, off, 16);
            t3 += __shfl_xor(t3, off, 16);
        }
        float w0 = __expf(fminf(t0 * SC, 70.f));
        float w1 = __expf(fminf(t1 * SC, 70.f));
        float w2 = __expf(fminf(t2 * SC, 70.f));
        float w3 = __expf(fminf(t3 * SC, 70.f));
        l += (w0 + w1) + (w2 + w3);
        a0 += w0 * lo16(v0.x) + w1 * lo16(v1.x) + w2 * lo16(v2.x) + w3 * lo16(v3.x);
        a1 += w0 * hi16(v0.x) + w1 * hi16(v1.x) + w2 * hi16(v2.x) + w3 * hi16(v3.x);
        a2 += w0 * lo16(v0.y) + w1 * lo16(v1.y) + w2 * lo16(v2.y) + w3 * lo16(v3.y);
        a3 += w0 * hi16(v0.y) + w1 * hi16(v1.y) + w2 * hi16(v2.y) + w3 * hi16(v3.y);
        a4 += w0 * lo16(v0.z) + w1 * lo16(v1.z) + w2 * lo16(v2.z) + w3 * lo16(v3.z);
        a5 += w0 * hi16(v0.z) + w1 * hi16(v1.z) + w2 * hi16(v2.z) + w3 * hi16(v3.z);
        a6 += w0 * lo16(v0.w) + w1 * lo16(v1.w) + w2 * lo16(v2.w) + w3 * lo16(v3.w);
        a7 += w0 * hi16(v0.w) + w1 * hi16(v1.w) + w2 * hi16(v2.w) + w3 * hi16(v3.w);
    }
    for (; p < p1; p++) {
        const u16* b = kv + (long)es[p] * 256 + lane * 8;
        uint4 kw = *(const uint4*)b;
        uint4 vw = *(const uint4*)(b + 128);
        float t = q0 * lo16(kw.x) + q1 * hi16(kw.x) + q2 * lo16(kw.y) + q3 * hi16(kw.y) +
                  q4 * lo16(kw.z) + q5 * hi16(kw.z) + q6 * lo16(kw.w) + q7 * hi16(kw.w);
#pragma unroll
        for (int off = 8; off >= 1; off >>= 1) t += __shfl_xor(t, off, 16);
        float w = __expf(fminf(t * SC, 70.f));
        l += w;
        a0 += w * lo16(vw.x);
        a1 += w * hi16(vw.x);
        a2 += w * lo16(vw.y);
        a3 += w * hi16(vw.y);
        a4 += w * lo16(vw.z);
        a5 += w * hi16(vw.z);
        a6 += w * lo16(vw.w);
        a7 += w * hi16(vw.w);
    }
    float invl = (l > 0.f) ? 1.0f / l : 0.f;
    uint4 sw = *(const uint4*)(skip + (long)node * 128 + lane * 8);
    float4 oa, ob;
    oa.x = fmaxf(a0 * invl + lo16(sw.x), 0.f);
    oa.y = fmaxf(a1 * invl + hi16(sw.x), 0.f);
    oa.z = fmaxf(a2 * invl + lo16(sw.y), 0.f);
    oa.w = fmaxf(a3 * invl + hi16(sw.y), 0.f);
    ob.x = fmaxf(a4 * invl + lo16(sw.z), 0.f);
    ob.y = fmaxf(a5 * invl + hi16(sw.z), 0.f);
    ob.z = fmaxf(a6 * invl + lo16(sw.w), 0.f);
    ob.w = fmaxf(a7 * invl + hi16(sw.w), 0.f);
    *(float4*)(out + (long)node * 128 + lane * 8) = oa;
    *(float4*)(out + (long)node * 128 + lane * 8 + 4) = ob;
}

extern "C" void kernel_launch(void* const* d_in, const int* in_sizes, int n_in,
                              void* d_out, int out_size, void* d_ws, size_t ws_size,
                              hipStream_t stream) {
    const float* x = (const float*)d_in[0];
    const int* ei = (const int*)d_in[1];
    const int* et = (const int*)d_in[2];
    const float* rw = (const float*)d_in[3];
    const float* root = (const float*)d_in[4];
    const float* rbias = (const float*)d_in[5];
    const float* Wq = (const float*)d_in[6];
    const float* bq = (const float*)d_in[7];
    const float* Wk = (const float*)d_in[8];
    const float* bk = (const float*)d_in[9];
    const float* Wv = (const float*)d_in[10];
    const float* bv = (const float*)d_in[11];
    const float* Ws = (const float*)d_in[12];
    const float* bs = (const float*)d_in[13];

    char* ws = (char*)d_ws;
    size_t off = 0;
    auto alloc = [&](size_t b) {
        size_t o = off;
        off = (off + b + 255) & ~(size_t)255;
        return o;
    };
    u16* pre = (u16*)(ws + alloc((size_t)NN * 1152 * 2));
    u16* h = (u16*)(ws + alloc((size_t)NN * 128 * 2));
    u16* qv = (u16*)(ws + alloc((size_t)NN * 128 * 2));
    u16* kv = (u16*)(ws + alloc((size_t)NN * 256 * 2));
    u16* skip = (u16*)(ws + alloc((size_t)NN * 128 * 2));
    u16* xb = (u16*)(ws + alloc((size_t)NN * 128 * 2));
    u16* wt1 = (u16*)(ws + alloc((size_t)128 * 1152 * 2));
    u16* wt2 = (u16*)(ws + alloc((size_t)4 * 128 * 128 * 2));
    float* bcat = (float*)(ws + alloc((size_t)512 * 4));
    int* cnt = (int*)(ws + alloc((size_t)NN * 8 * 4));
    int* row_off = (int*)(ws + alloc((size_t)(NN + 1) * 4));
    int* srt = (int*)(ws + alloc((size_t)NN * 8 * 4));
    int* deg_pref = (int*)(ws + alloc((size_t)NN * 4));
    int* blk_sums = (int*)(ws + alloc((size_t)128 * 4));
    int* rank = (int*)(ws + alloc((size_t)EE * 4));
    int* es = (int*)(ws + alloc((size_t)EE * 4));
    (void)ws_size;
    (void)in_sizes;
    (void)n_in;
    (void)out_size;

    prep_all<<<(ZP_N + CX_N + WP_N + 255) / 256, 256, 0, stream>>>(
        x, rw, root, Wq, Wk, Wv, Ws, bq, bk, bv, bs, cnt, xb, wt1, wt2, bcat);

    count_rank<<<(EE + 1023) / 1024, 256, 0, stream>>>(ei, et, cnt, rank);
    scan_phase1<<<SCAN_BLOCKS, 256, 0, stream>>>(cnt, deg_pref, blk_sums);
    scan_phase2<<<1, 128, 0, stream>>>(blk_sums);
    scan_phase3<<<SCAN_BLOCKS, 256, 0, stream>>>(cnt, deg_pref, blk_sums, row_off, srt);
    scatter_kernel<<<(EE + 1023) / 1024, 256, 0, stream>>>(ei, et, srt, rank, es);

    rgcn_agg<<<(NN * 9 + 15) / 16, 256, 0, stream>>>(xb, srt, cnt, es, pre);

    gemm_bm32<<<(NN + 31) / 32, 256, 0, stream>>>(pre, wt1, rbias, h, NN);
    gemm_qkvs<<<dim3((NN + 63) / 64, 4), 256, 0, stream>>>(h, wt2, bcat, qv, kv, skip, NN);

    attn_kernel<<<(NN + 15) / 16, 256, 0, stream>>>(qv, kv, skip, row_off, es, (float*)d_out);
}